// Round 11
// baseline (436.879 us; speedup 1.0000x reference)
//
#include <hip/hip_runtime.h>
#include <hip/hip_bf16.h>

#define IN_DIM 256
#define H1 512
#define H2 128
#define LDA 264   // LDS row stride in shorts for 256-short rows (+8 pad)
#define SCAN_CHUNK 4096

typedef unsigned short u16;
typedef unsigned long long u64;
typedef __attribute__((ext_vector_type(8))) short short8;
typedef __attribute__((ext_vector_type(4))) float floatx4;

__device__ __forceinline__ u16 f2bf(float f) {
    union { float f; unsigned u; } c; c.f = f;
    unsigned u = c.u;
    return (u16)((u + 0x7fffu + ((u >> 16) & 1u)) >> 16);
}
__device__ __forceinline__ float bflo(unsigned w) {
    union { unsigned u; float f; } c; c.u = w << 16; return c.f;
}
__device__ __forceinline__ float bfhi(unsigned w) {
    union { unsigned u; float f; } c; c.u = w & 0xffff0000u; return c.f;
}

// ---- fused prep: mask1 bit-pack + degree histogram + W1/W2 transpose-cast --
// pack layout: bit i of word [g*4+j] = mask[g*256 + 4*i + j]  (g = wave index).

__global__ __launch_bounds__(256) void prep_kernel(const int4* __restrict__ mask4,
        u64* __restrict__ bits, int total4,
        const int* __restrict__ dstA, int* __restrict__ counts, int E, int n,
        const float* __restrict__ W1, u16* __restrict__ w1t,
        const float* __restrict__ W2, u16* __restrict__ w2t,
        int PB, int HB, int T1B) {
    int b = blockIdx.x;
    if (b < PB) {                    // ---- pack mask1
        int gid = b * 256 + threadIdx.x;
        int lane = threadIdx.x & 63;
        int4 v = (gid < total4) ? mask4[gid] : make_int4(0, 0, 0, 0);
        u64 b0 = __ballot(v.x != 0);
        u64 b1 = __ballot(v.y != 0);
        u64 b2 = __ballot(v.z != 0);
        u64 b3 = __ballot(v.w != 0);
        u64 sel = (lane == 0) ? b0 : (lane == 1) ? b1 : (lane == 2) ? b2 : b3;
        if (lane < 4 && gid < total4)
            bits[(size_t)(gid >> 6) * 4 + lane] = sel;
    } else if (b < PB + HB) {        // ---- histogram of dst degrees
        int e = (b - PB) * 256 + threadIdx.x;
        if (e < E) {
            int d = dstA[e];
            if ((unsigned)d < (unsigned)n) atomicAdd(&counts[d], 1);
        }
    } else if (b < PB + HB + T1B) {  // ---- W1^T cast (256x512 -> 512x256)
        int idx = (b - PB - HB) * 256 + threadIdx.x;
        if (idx < IN_DIM * H1) {
            int k = idx >> 9, c = idx & (H1 - 1);
            w1t[c * IN_DIM + k] = f2bf(W1[idx]);
        }
    } else {                         // ---- W2^T cast (512x128 -> 128x512)
        int idx = (b - PB - HB - T1B) * 256 + threadIdx.x;
        if (idx < H1 * H2) {
            int k = idx >> 7, c = idx & (H2 - 1);
            w2t[c * H1 + k] = f2bf(W2[idx]);
        }
    }
}

// ---- 3-dispatch hierarchical scan over EVEN-CEILED counts -----------------

__global__ __launch_bounds__(256) void partial_sum_kernel(const int* __restrict__ counts,
        int* __restrict__ partials, int n) {
    int t = threadIdx.x;
    int base = blockIdx.x * SCAN_CHUNK + t * 16;
    int s = 0;
    int m = (base < n) ? min(16, n - base) : 0;
    for (int i = 0; i < m; ++i) s += (counts[base + i] + 1) & ~1;
    __shared__ int red[256];
    red[t] = s;
    __syncthreads();
    for (int off = 128; off > 0; off >>= 1) {
        if (t < off) red[t] += red[t + off];
        __syncthreads();
    }
    if (t == 0) partials[blockIdx.x] = red[0];
}

// also zeroes the sentinel row n of ts while this tiny kernel is here
__global__ void scan_partials_kernel(int* __restrict__ partials, int nb,
                                     unsigned* __restrict__ ts_zero_row) {
    int t = threadIdx.x;
    if (t < 64) ts_zero_row[t] = 0;   // ts row n: 128 bf16 = 64 uints
    if (t == 0 && blockIdx.x == 0) {
        int run = 0;
        for (int i = 0; i < nb; ++i) { int c = partials[i]; partials[i] = run; run += c; }
        partials[nb] = run;   // total (padded)
    }
}

__global__ __launch_bounds__(256) void scan_emit_kernel(const int* __restrict__ counts,
        const int* __restrict__ partials, int* __restrict__ row_start,
        int* __restrict__ cursor, float* __restrict__ dis,
        int* __restrict__ csr, int n, int nb) {
    int t = threadIdx.x;
    int base = blockIdx.x * SCAN_CHUNK + t * 16;
    int cnt[16];
    int s = 0;
    int m = (base < n) ? min(16, n - base) : 0;
    for (int i = 0; i < m; ++i) { cnt[i] = counts[base + i]; s += (cnt[i] + 1) & ~1; }
    __shared__ int red[256];
    red[t] = s;
    __syncthreads();
    for (int off = 1; off < 256; off <<= 1) {
        int v = red[t];
        int vo = (t >= off) ? red[t - off] : 0;
        __syncthreads();
        red[t] = v + vo;
        __syncthreads();
    }
    int run = partials[blockIdx.x] + (t ? red[t - 1] : 0);
    for (int i = 0; i < m; ++i) {
        int c = cnt[i];
        row_start[base + i] = run;
        cursor[base + i] = run;
        dis[base + i] = rsqrtf((float)(c + 1));   // deg = REAL indeg + self-loop
        if (c & 1) csr[run + c] = n;              // pad slot -> sentinel zero row
        run += (c + 1) & ~1;
    }
    if (blockIdx.x == 0 && t == 0) row_start[n] = partials[nb];
}

__global__ void scatter_kernel(const int* __restrict__ srcA, const int* __restrict__ dstA,
                               int* __restrict__ cursor, int* __restrict__ csr,
                               int E, int n) {
    int e = blockIdx.x * blockDim.x + threadIdx.x;
    if (e < E) {
        int d = dstA[e];
        int s = srcA[e];
        if ((unsigned)d < (unsigned)n && (unsigned)s < (unsigned)n) {
            int p = atomicAdd(&cursor[d], 1);
            csr[p] = s;
        }
    }
}

// xs[i,:] = bf16(dis[i] * x[i,:]) for i<n;  xs[n,:] = 0 (sentinel row)
__global__ void scale_cast_kernel(const float* __restrict__ x, const float* __restrict__ dis,
                                  u16* __restrict__ xs, int n) {
    int gid = blockIdx.x * blockDim.x + threadIdx.x;
    int total = (n + 1) * (IN_DIM / 4);
    if (gid >= total) return;
    int node = gid >> 6;
    uint2 o = make_uint2(0, 0);
    if (node < n) {
        float4 v = ((const float4*)x)[gid];
        float d = dis[node];
        o.x = (unsigned)f2bf(v.x * d) | ((unsigned)f2bf(v.y * d) << 16);
        o.y = (unsigned)f2bf(v.z * d) | ((unsigned)f2bf(v.w * d) << 16);
    }
    ((uint2*)xs)[gid] = o;
}

// ---- aggregation 1 (dual-row gather, padded-even CSR) ---------------------

__global__ __launch_bounds__(256) void agg1_kernel(const u16* __restrict__ xs,
        const int* __restrict__ row_start, const int* __restrict__ csr,
        const float* __restrict__ dis, u16* __restrict__ aggx, int n) {
    int gid = blockIdx.x * blockDim.x + threadIdx.x;
    int w = gid >> 6, lane = gid & 63;
    if (w >= n) return;
    const uint4* base = (const uint4*)xs;
    int half = lane >> 5, hl = lane & 31;
    float a0 = 0.f, a1 = 0.f, a2 = 0.f, a3 = 0.f, a4 = 0.f, a5 = 0.f, a6 = 0.f, a7 = 0.f;
    if (half == 0) {
        uint4 u = base[(size_t)w * 32 + hl];
        a0 = bflo(u.x); a1 = bfhi(u.x); a2 = bflo(u.y); a3 = bfhi(u.y);
        a4 = bflo(u.z); a5 = bfhi(u.z); a6 = bflo(u.w); a7 = bfhi(u.w);
    }
    int b = row_start[w], e = row_start[w + 1];
    int i = b;
    for (; i + 8 <= e; i += 8) {
        int s0 = csr[i + half],     s1 = csr[i + 2 + half];
        int s2 = csr[i + 4 + half], s3 = csr[i + 6 + half];
        uint4 u0 = base[(size_t)s0 * 32 + hl];
        uint4 u1 = base[(size_t)s1 * 32 + hl];
        uint4 u2 = base[(size_t)s2 * 32 + hl];
        uint4 u3 = base[(size_t)s3 * 32 + hl];
        a0 += (bflo(u0.x) + bflo(u1.x)) + (bflo(u2.x) + bflo(u3.x));
        a1 += (bfhi(u0.x) + bfhi(u1.x)) + (bfhi(u2.x) + bfhi(u3.x));
        a2 += (bflo(u0.y) + bflo(u1.y)) + (bflo(u2.y) + bflo(u3.y));
        a3 += (bfhi(u0.y) + bfhi(u1.y)) + (bfhi(u2.y) + bfhi(u3.y));
        a4 += (bflo(u0.z) + bflo(u1.z)) + (bflo(u2.z) + bflo(u3.z));
        a5 += (bfhi(u0.z) + bfhi(u1.z)) + (bfhi(u2.z) + bfhi(u3.z));
        a6 += (bflo(u0.w) + bflo(u1.w)) + (bflo(u2.w) + bflo(u3.w));
        a7 += (bfhi(u0.w) + bfhi(u1.w)) + (bfhi(u2.w) + bfhi(u3.w));
    }
    for (; i < e; i += 2) {
        int s = csr[i + half];
        uint4 u = base[(size_t)s * 32 + hl];
        a0 += bflo(u.x); a1 += bfhi(u.x); a2 += bflo(u.y); a3 += bfhi(u.y);
        a4 += bflo(u.z); a5 += bfhi(u.z); a6 += bflo(u.w); a7 += bfhi(u.w);
    }
    a0 += __shfl_xor(a0, 32); a1 += __shfl_xor(a1, 32);
    a2 += __shfl_xor(a2, 32); a3 += __shfl_xor(a3, 32);
    a4 += __shfl_xor(a4, 32); a5 += __shfl_xor(a5, 32);
    a6 += __shfl_xor(a6, 32); a7 += __shfl_xor(a7, 32);
    if (half == 0) {
        float dd = dis[w];
        uint4 o;
        o.x = (unsigned)f2bf(a0 * dd) | ((unsigned)f2bf(a1 * dd) << 16);
        o.y = (unsigned)f2bf(a2 * dd) | ((unsigned)f2bf(a3 * dd) << 16);
        o.z = (unsigned)f2bf(a4 * dd) | ((unsigned)f2bf(a5 * dd) << 16);
        o.w = (unsigned)f2bf(a6 * dd) | ((unsigned)f2bf(a7 * dd) << 16);
        ((uint4*)aggx)[(size_t)w * 32 + hl] = o;
    }
}

// ---- FUSED GEMM: ts = dis * ( dropout(prelu(aggx@W1+b1)) @ W2 ) -----------
// One 64-row block does both layers; feat1 tile lives only in LDS (never HBM).
// Phase 1 (per 256-col half): acc1 = A(LDS) @ W1t(global, L2-hot), epilogue
// (bias+prelu+dropout-bits) -> Fs (LDS bf16). Phase 2: acc2 += Fs @ W2t.
// A staged ONCE (the R9 lesson: A re-reads from global killed perf).

__global__ __launch_bounds__(256) void gemm_fused_kernel(const u16* __restrict__ A,
        const u16* __restrict__ W1t, const float* __restrict__ b1,
        const float* __restrict__ a_p, const u64* __restrict__ mbits,
        const u16* __restrict__ W2t, const float* __restrict__ dis,
        u16* __restrict__ ts, int M) {
    __shared__ __align__(16) u16 As[64 * LDA];   // 33.8 KB  (A tile, 64x256)
    __shared__ __align__(16) u16 Fs[64 * LDA];   // 33.8 KB  (feat1 half-tile, 64x256)
    __shared__ u64 Mb[64 * 9];                   // 4.6 KB   (mask bits, 8 u64/row, stride 9)
    int tid = threadIdx.x;
    int wave = tid >> 6, lane = tid & 63;
    int quad = lane >> 4, l16 = lane & 15;
    int m0 = blockIdx.x * 64;

    // stage A (64 rows x 32 x 16B) and mask bits
    for (int u = tid; u < 2048; u += 256) {
        int row = u >> 5, seg = u & 31;
        uint4 av = make_uint4(0, 0, 0, 0);
        int gr = m0 + row;
        if (gr < M) av = *(const uint4*)&A[(size_t)gr * IN_DIM + seg * 8];
        *(uint4*)&As[row * LDA + seg * 8] = av;
    }
    for (int u = tid; u < 512; u += 256) {
        int row = u >> 3, j = u & 7;
        int gr = m0 + row;
        Mb[row * 9 + j] = (gr < M) ? mbits[(size_t)gr * 8 + j] : 0;
    }
    __syncthreads();

    floatx4 acc2[8];
#pragma unroll
    for (int i = 0; i < 8; i++) acc2[i] = (floatx4){0.f, 0.f, 0.f, 0.f};
    float alpha = a_p[0];

#pragma unroll
    for (int h = 0; h < 2; h++) {
        // ---- phase 1: acc1 = A @ W1t[h-half]  (wave covers 64 rows x 64 cols)
        floatx4 acc1[4][4];
#pragma unroll
        for (int i = 0; i < 4; i++)
#pragma unroll
            for (int j = 0; j < 4; j++) acc1[i][j] = (floatx4){0.f, 0.f, 0.f, 0.f};
        const u16* bptr1[4];
#pragma unroll
        for (int nt = 0; nt < 4; nt++)
            bptr1[nt] = W1t + (size_t)(h * 256 + wave * 64 + nt * 16 + l16) * IN_DIM + quad * 8;
        float bias_v[4];
#pragma unroll
        for (int nt = 0; nt < 4; nt++)
            bias_v[nt] = b1[h * 256 + wave * 64 + nt * 16 + l16];
#pragma unroll
        for (int k0 = 0; k0 < 256; k0 += 64) {
            short8 bf[4][2], af[4][2];
#pragma unroll
            for (int nt = 0; nt < 4; nt++) {
                bf[nt][0] = *(const short8*)(bptr1[nt] + k0);
                bf[nt][1] = *(const short8*)(bptr1[nt] + k0 + 32);
            }
#pragma unroll
            for (int mt = 0; mt < 4; mt++) {
                af[mt][0] = *(const short8*)&As[(mt * 16 + l16) * LDA + k0 + quad * 8];
                af[mt][1] = *(const short8*)&As[(mt * 16 + l16) * LDA + k0 + 32 + quad * 8];
            }
#pragma unroll
            for (int mt = 0; mt < 4; mt++)
#pragma unroll
                for (int nt = 0; nt < 4; nt++) {
                    acc1[mt][nt] = __builtin_amdgcn_mfma_f32_16x16x32_bf16(
                        af[mt][0], bf[nt][0], acc1[mt][nt], 0, 0, 0);
                    acc1[mt][nt] = __builtin_amdgcn_mfma_f32_16x16x32_bf16(
                        af[mt][1], bf[nt][1], acc1[mt][nt], 0, 0, 0);
                }
        }

        __syncthreads();   // h=1: wait for all phase-2 reads of Fs before overwrite
        // ---- phase-1 epilogue -> Fs (bias, prelu, dropout via bits)
#pragma unroll
        for (int mt = 0; mt < 4; mt++) {
#pragma unroll
            for (int r = 0; r < 4; r++) {
                int row_l = mt * 16 + quad * 4 + r;
#pragma unroll
                for (int nt = 0; nt < 4; nt++) {
                    int col_l = wave * 64 + nt * 16 + l16;
                    float v = acc1[mt][nt][r] + bias_v[nt];
                    v = (v >= 0.f) ? v : alpha * v;
                    u64 wbits = Mb[row_l * 9 + h * 4 + (l16 & 3)];
                    int bit = wave * 16 + nt * 4 + (l16 >> 2);   // (col>>2)&63
                    v = ((wbits >> bit) & 1ull) ? v * 2.0f : 0.0f;
                    Fs[row_l * LDA + col_l] = f2bf(v);
                }
            }
        }
        __syncthreads();   // Fs visible to all waves

        // ---- phase 2: acc2 += Fs @ W2t[k-half]  (wave covers 16 rows x 128 cols)
        const u16* bptr2 = W2t + (size_t)l16 * H1 + h * 256 + quad * 8;
#pragma unroll
        for (int k0 = 0; k0 < 256; k0 += 32) {
            short8 af2 = *(const short8*)&Fs[(wave * 16 + l16) * LDA + k0 + quad * 8];
            short8 bf2[8];
#pragma unroll
            for (int nt2 = 0; nt2 < 8; nt2++)
                bf2[nt2] = *(const short8*)(bptr2 + (size_t)nt2 * 16 * H1 + k0);
#pragma unroll
            for (int nt2 = 0; nt2 < 8; nt2++)
                acc2[nt2] = __builtin_amdgcn_mfma_f32_16x16x32_bf16(
                    af2, bf2[nt2], acc2[nt2], 0, 0, 0);
        }
    }

    // ---- ts epilogue: dis scale, direct store
#pragma unroll
    for (int r = 0; r < 4; r++) {
        int row = m0 + wave * 16 + quad * 4 + r;
        if (row >= M) continue;
        float dd = dis[row];
#pragma unroll
        for (int nt2 = 0; nt2 < 8; nt2++)
            ts[(size_t)row * H2 + nt2 * 16 + l16] = f2bf(acc2[nt2][r] * dd);
    }
}

// ---- aggregation 2 + epilogue (dual-row gather, padded-even CSR) ----------

__global__ __launch_bounds__(256) void agg2_kernel(const u16* __restrict__ ts,
        const int* __restrict__ row_start, const int* __restrict__ csr,
        const float* __restrict__ dis, const float* __restrict__ b2,
        const float* __restrict__ a_p, const int* __restrict__ mask,
        float* __restrict__ out, int n) {
    int gid = blockIdx.x * blockDim.x + threadIdx.x;
    int w = gid >> 6, lane = gid & 63;
    if (w >= n) return;
    const uint2* base = (const uint2*)ts;
    int half = lane >> 5, hl = lane & 31;
    float a0 = 0.f, a1 = 0.f, a2 = 0.f, a3 = 0.f;
    if (half == 0) {
        uint2 u = base[(size_t)w * 32 + hl];
        a0 = bflo(u.x); a1 = bfhi(u.x); a2 = bflo(u.y); a3 = bfhi(u.y);
    }
    int b = row_start[w], e = row_start[w + 1];
    int i = b;
    for (; i + 8 <= e; i += 8) {
        int s0 = csr[i + half],     s1 = csr[i + 2 + half];
        int s2 = csr[i + 4 + half], s3 = csr[i + 6 + half];
        uint2 u0 = base[(size_t)s0 * 32 + hl];
        uint2 u1 = base[(size_t)s1 * 32 + hl];
        uint2 u2 = base[(size_t)s2 * 32 + hl];
        uint2 u3 = base[(size_t)s3 * 32 + hl];
        a0 += (bflo(u0.x) + bflo(u1.x)) + (bflo(u2.x) + bflo(u3.x));
        a1 += (bfhi(u0.x) + bfhi(u1.x)) + (bfhi(u2.x) + bfhi(u3.x));
        a2 += (bflo(u0.y) + bflo(u1.y)) + (bflo(u2.y) + bflo(u3.y));
        a3 += (bfhi(u0.y) + bfhi(u1.y)) + (bfhi(u2.y) + bfhi(u3.y));
    }
    for (; i < e; i += 2) {
        int s = csr[i + half];
        uint2 u = base[(size_t)s * 32 + hl];
        a0 += bflo(u.x); a1 += bfhi(u.x); a2 += bflo(u.y); a3 += bfhi(u.y);
    }
    a0 += __shfl_xor(a0, 32); a1 += __shfl_xor(a1, 32);
    a2 += __shfl_xor(a2, 32); a3 += __shfl_xor(a3, 32);
    if (half == 0) {
        float dd = dis[w];
        float alpha = a_p[0];
        float4 bb = ((const float4*)b2)[hl];
        float v0 = dd * a0 + bb.x;
        float v1 = dd * a1 + bb.y;
        float v2 = dd * a2 + bb.z;
        float v3 = dd * a3 + bb.w;
        v0 = (v0 >= 0.f) ? v0 : alpha * v0;
        v1 = (v1 >= 0.f) ? v1 : alpha * v1;
        v2 = (v2 >= 0.f) ? v2 : alpha * v2;
        v3 = (v3 >= 0.f) ? v3 : alpha * v3;
        int4 m = ((const int4*)mask)[(size_t)w * 32 + hl];
        v0 = m.x ? v0 * 2.f : 0.f;
        v1 = m.y ? v1 * 2.f : 0.f;
        v2 = m.z ? v2 * 2.f : 0.f;
        v3 = m.w ? v3 * 2.f : 0.f;
        ((float4*)out)[(size_t)w * 32 + hl] = make_float4(v0, v1, v2, v3);
    }
}

// ---- launch ---------------------------------------------------------------

extern "C" void kernel_launch(void* const* d_in, const int* in_sizes, int n_in,
                              void* d_out, int out_size, void* d_ws, size_t ws_size,
                              hipStream_t stream) {
    const float* x  = (const float*)d_in[0];
    const int* ei   = (const int*)d_in[1];
    const float* W1 = (const float*)d_in[2];
    const float* b1 = (const float*)d_in[3];
    const float* W2 = (const float*)d_in[4];
    const float* b2 = (const float*)d_in[5];
    const float* ap = (const float*)d_in[6];
    const int* mask1 = (const int*)d_in[7];
    const int* mask2 = (const int*)d_in[8];

    int n = in_sizes[0] / IN_DIM;      // 50000
    int E = in_sizes[1] / 2;           // 400000
    const int* srcA = ei;
    const int* dstA = ei + E;

    // ws layout: xs (n+1 rows incl sentinel), ts (n+1 rows), bits1 (own slot —
    // the fused kernel reads bits while writing ts, so no aliasing), w1t, w2t,
    // graph arrays.  aggx lives in d_out (dead before agg2 rewrites d_out).
    char* p = (char*)d_ws;
    auto alloc = [&](size_t bytes) {
        char* r = p;
        p += (bytes + 255) & ~(size_t)255;
        return r;
    };
    u16* xs        = (u16*)alloc((size_t)(n + 1) * IN_DIM * 2);
    u16* ts        = (u16*)alloc((size_t)(n + 1) * H2 * 2);
    u64* bits1     = (u64*)alloc((size_t)n * (H1 / 64) * 8);
    u16* w1t       = (u16*)alloc((size_t)IN_DIM * H1 * 2);
    u16* w2t       = (u16*)alloc((size_t)H1 * H2 * 2);
    float* dis     = (float*)alloc((size_t)n * 4);
    int* counts    = (int*)alloc((size_t)n * 4);
    int* cursor    = (int*)alloc((size_t)n * 4);
    int* row_start = (int*)alloc(((size_t)n + 1) * 4);
    int* csr       = (int*)alloc(((size_t)E + n + 64) * 4);
    int nscan = (n + SCAN_CHUNK - 1) / SCAN_CHUNK;
    int* partials  = (int*)alloc(((size_t)nscan + 1) * 4);
    u16* aggx      = (u16*)d_out;
    if ((size_t)(p - (char*)d_ws) > ws_size) return;

    const int tpb = 256;
    int total4 = n * H1 / 4;
    int PB = (total4 + tpb - 1) / tpb;
    int HB = (E + tpb - 1) / tpb;
    int T1B = (IN_DIM * H1 + tpb - 1) / tpb;
    int T2B = (H1 * H2 + tpb - 1) / tpb;
    hipMemsetAsync(counts, 0, (size_t)n * 4, stream);
    prep_kernel<<<PB + HB + T1B + T2B, tpb, 0, stream>>>((const int4*)mask1, bits1, total4,
        dstA, counts, E, n, W1, w1t, W2, w2t, PB, HB, T1B);
    partial_sum_kernel<<<nscan, tpb, 0, stream>>>(counts, partials, n);
    scan_partials_kernel<<<1, 64, 0, stream>>>(partials, nscan,
        (unsigned*)(ts + (size_t)n * H2));
    scan_emit_kernel<<<nscan, tpb, 0, stream>>>(counts, partials, row_start, cursor, dis,
                                                csr, n, nscan);
    scatter_kernel<<<(E + tpb - 1) / tpb, tpb, 0, stream>>>(srcA, dstA, cursor, csr, E, n);
    scale_cast_kernel<<<(((n + 1) * (IN_DIM / 4)) + tpb - 1) / tpb, tpb, 0, stream>>>(x, dis, xs, n);
    agg1_kernel<<<(n * 64 + tpb - 1) / tpb, tpb, 0, stream>>>(xs, row_start, csr, dis, aggx, n);
    gemm_fused_kernel<<<(n + 63) / 64, tpb, 0, stream>>>(aggx, w1t, b1, ap, bits1,
                                                         w2t, dis, ts, n);
    agg2_kernel<<<(n * 64 + tpb - 1) / tpb, tpb, 0, stream>>>(ts, row_start, csr, dis, b2, ap,
                                                              mask2, (float*)d_out, n);
}

// Round 12
// 408.424 us; speedup vs baseline: 1.0697x; 1.0697x over previous
//
#include <hip/hip_runtime.h>
#include <hip/hip_bf16.h>

#define IN_DIM 256
#define H1 512
#define H2 128
#define BM 128
#define BKK 64   // K-tile depth: 4 K-iters for gemm1, 8 for gemm2
#define LDT 72   // LDS row stride in shorts for 64-short rows (+8 pad)
#define SCAN_CHUNK 4096  // 256 threads x 16 elements

typedef unsigned short u16;
typedef unsigned long long u64;
typedef __attribute__((ext_vector_type(8))) short short8;
typedef __attribute__((ext_vector_type(4))) float floatx4;

__device__ __forceinline__ u16 f2bf(float f) {
    union { float f; unsigned u; } c; c.f = f;
    unsigned u = c.u;
    return (u16)((u + 0x7fffu + ((u >> 16) & 1u)) >> 16);
}
__device__ __forceinline__ float bflo(unsigned w) {
    union { unsigned u; float f; } c; c.u = w << 16; return c.f;
}
__device__ __forceinline__ float bfhi(unsigned w) {
    union { unsigned u; float f; } c; c.u = w & 0xffff0000u; return c.f;
}

// ---- fused prep: mask1 bit-pack + degree histogram + W1/W2 transpose-cast --
// pack layout: bit i of word [g*4+j] = mask[g*256 + 4*i + j]  (g = wave index).

__global__ __launch_bounds__(256) void prep_kernel(const int4* __restrict__ mask4,
        u64* __restrict__ bits, int total4,
        const int* __restrict__ dstA, int* __restrict__ counts, int E, int n,
        const float* __restrict__ W1, u16* __restrict__ w1t,
        const float* __restrict__ W2, u16* __restrict__ w2t,
        int PB, int HB, int T1B) {
    int b = blockIdx.x;
    if (b < PB) {                    // ---- pack mask1
        int gid = b * 256 + threadIdx.x;
        int lane = threadIdx.x & 63;
        int4 v = (gid < total4) ? mask4[gid] : make_int4(0, 0, 0, 0);
        u64 b0 = __ballot(v.x != 0);
        u64 b1 = __ballot(v.y != 0);
        u64 b2 = __ballot(v.z != 0);
        u64 b3 = __ballot(v.w != 0);
        u64 sel = (lane == 0) ? b0 : (lane == 1) ? b1 : (lane == 2) ? b2 : b3;
        if (lane < 4 && gid < total4)
            bits[(size_t)(gid >> 6) * 4 + lane] = sel;
    } else if (b < PB + HB) {        // ---- histogram of dst degrees
        int e = (b - PB) * 256 + threadIdx.x;
        if (e < E) {
            int d = dstA[e];
            if ((unsigned)d < (unsigned)n) atomicAdd(&counts[d], 1);
        }
    } else if (b < PB + HB + T1B) {  // ---- W1^T cast (256x512 -> 512x256)
        int idx = (b - PB - HB) * 256 + threadIdx.x;
        if (idx < IN_DIM * H1) {
            int k = idx >> 9, c = idx & (H1 - 1);
            w1t[c * IN_DIM + k] = f2bf(W1[idx]);
        }
    } else {                         // ---- W2^T cast (512x128 -> 128x512)
        int idx = (b - PB - HB - T1B) * 256 + threadIdx.x;
        if (idx < H1 * H2) {
            int k = idx >> 7, c = idx & (H2 - 1);
            w2t[c * H1 + k] = f2bf(W2[idx]);
        }
    }
}

// ---- 3-dispatch hierarchical scan over EVEN-CEILED counts -----------------
// pads every adjacency list to even length; the pad slot holds sentinel index n
// (a zero row in xs/ts) so the dual-row agg loops need no remainder handling.

__global__ __launch_bounds__(256) void partial_sum_kernel(const int* __restrict__ counts,
        int* __restrict__ partials, int n) {
    int t = threadIdx.x;
    int base = blockIdx.x * SCAN_CHUNK + t * 16;
    int s = 0;
    int m = (base < n) ? min(16, n - base) : 0;
    for (int i = 0; i < m; ++i) s += (counts[base + i] + 1) & ~1;
    __shared__ int red[256];
    red[t] = s;
    __syncthreads();
    for (int off = 128; off > 0; off >>= 1) {
        if (t < off) red[t] += red[t + off];
        __syncthreads();
    }
    if (t == 0) partials[blockIdx.x] = red[0];
}

// also zeroes the sentinel row n of ts while this tiny kernel is here
__global__ void scan_partials_kernel(int* __restrict__ partials, int nb,
                                     unsigned* __restrict__ ts_zero_row) {
    int t = threadIdx.x;
    if (t < 64) ts_zero_row[t] = 0;   // ts row n: 128 bf16 = 64 uints
    if (t == 0 && blockIdx.x == 0) {
        int run = 0;
        for (int i = 0; i < nb; ++i) { int c = partials[i]; partials[i] = run; run += c; }
        partials[nb] = run;   // total (padded)
    }
}

__global__ __launch_bounds__(256) void scan_emit_kernel(const int* __restrict__ counts,
        const int* __restrict__ partials, int* __restrict__ row_start,
        int* __restrict__ cursor, float* __restrict__ dis,
        int* __restrict__ csr, int n, int nb) {
    int t = threadIdx.x;
    int base = blockIdx.x * SCAN_CHUNK + t * 16;
    int cnt[16];
    int s = 0;
    int m = (base < n) ? min(16, n - base) : 0;
    for (int i = 0; i < m; ++i) { cnt[i] = counts[base + i]; s += (cnt[i] + 1) & ~1; }
    __shared__ int red[256];
    red[t] = s;
    __syncthreads();
    for (int off = 1; off < 256; off <<= 1) {   // inclusive Hillis-Steele
        int v = red[t];
        int vo = (t >= off) ? red[t - off] : 0;
        __syncthreads();
        red[t] = v + vo;
        __syncthreads();
    }
    int run = partials[blockIdx.x] + (t ? red[t - 1] : 0);
    for (int i = 0; i < m; ++i) {
        int c = cnt[i];
        row_start[base + i] = run;
        cursor[base + i] = run;
        dis[base + i] = rsqrtf((float)(c + 1));   // deg = REAL indeg + self-loop
        if (c & 1) csr[run + c] = n;              // pad slot -> sentinel zero row
        run += (c + 1) & ~1;
    }
    if (blockIdx.x == 0 && t == 0) row_start[n] = partials[nb];
}

__global__ void scatter_kernel(const int* __restrict__ srcA, const int* __restrict__ dstA,
                               int* __restrict__ cursor, int* __restrict__ csr,
                               int E, int n) {
    int e = blockIdx.x * blockDim.x + threadIdx.x;
    if (e < E) {
        int d = dstA[e];
        int s = srcA[e];
        if ((unsigned)d < (unsigned)n && (unsigned)s < (unsigned)n) {
            int p = atomicAdd(&cursor[d], 1);
            csr[p] = s;
        }
    }
}

// xs[i,:] = bf16(dis[i] * x[i,:]) for i<n;  xs[n,:] = 0 (sentinel row)
__global__ void scale_cast_kernel(const float* __restrict__ x, const float* __restrict__ dis,
                                  u16* __restrict__ xs, int n) {
    int gid = blockIdx.x * blockDim.x + threadIdx.x;
    int total = (n + 1) * (IN_DIM / 4);
    if (gid >= total) return;
    int node = gid >> 6;   // IN_DIM/4 == 64
    uint2 o = make_uint2(0, 0);
    if (node < n) {
        float4 v = ((const float4*)x)[gid];
        float d = dis[node];
        o.x = (unsigned)f2bf(v.x * d) | ((unsigned)f2bf(v.y * d) << 16);
        o.y = (unsigned)f2bf(v.z * d) | ((unsigned)f2bf(v.w * d) << 16);
    }
    ((uint2*)xs)[gid] = o;
}

// ---- aggregation 1: aggx[d] = bf16( dis[d] * (xs[d] + sum_{s in in(d)} xs[s]) ) -----
// Dual-row gather: lower/upper 32 lanes take rows j / j+1 at 16B/lane (uint4).

__global__ __launch_bounds__(256) void agg1_kernel(const u16* __restrict__ xs,
        const int* __restrict__ row_start, const int* __restrict__ csr,
        const float* __restrict__ dis, u16* __restrict__ aggx, int n) {
    int gid = blockIdx.x * blockDim.x + threadIdx.x;
    int w = gid >> 6, lane = gid & 63;
    if (w >= n) return;
    const uint4* base = (const uint4*)xs;       // 32 uint4 per 256-feat row
    int half = lane >> 5, hl = lane & 31;
    float a0 = 0.f, a1 = 0.f, a2 = 0.f, a3 = 0.f, a4 = 0.f, a5 = 0.f, a6 = 0.f, a7 = 0.f;
    if (half == 0) {                            // self-loop seed in lower half only
        uint4 u = base[(size_t)w * 32 + hl];
        a0 = bflo(u.x); a1 = bfhi(u.x); a2 = bflo(u.y); a3 = bfhi(u.y);
        a4 = bflo(u.z); a5 = bfhi(u.z); a6 = bflo(u.w); a7 = bfhi(u.w);
    }
    int b = row_start[w], e = row_start[w + 1];
    int i = b;
    for (; i + 8 <= e; i += 8) {
        int s0 = csr[i + half],     s1 = csr[i + 2 + half];
        int s2 = csr[i + 4 + half], s3 = csr[i + 6 + half];
        uint4 u0 = base[(size_t)s0 * 32 + hl];
        uint4 u1 = base[(size_t)s1 * 32 + hl];
        uint4 u2 = base[(size_t)s2 * 32 + hl];
        uint4 u3 = base[(size_t)s3 * 32 + hl];
        a0 += (bflo(u0.x) + bflo(u1.x)) + (bflo(u2.x) + bflo(u3.x));
        a1 += (bfhi(u0.x) + bfhi(u1.x)) + (bfhi(u2.x) + bfhi(u3.x));
        a2 += (bflo(u0.y) + bflo(u1.y)) + (bflo(u2.y) + bflo(u3.y));
        a3 += (bfhi(u0.y) + bfhi(u1.y)) + (bfhi(u2.y) + bfhi(u3.y));
        a4 += (bflo(u0.z) + bflo(u1.z)) + (bflo(u2.z) + bflo(u3.z));
        a5 += (bfhi(u0.z) + bfhi(u1.z)) + (bfhi(u2.z) + bfhi(u3.z));
        a6 += (bflo(u0.w) + bflo(u1.w)) + (bflo(u2.w) + bflo(u3.w));
        a7 += (bfhi(u0.w) + bfhi(u1.w)) + (bfhi(u2.w) + bfhi(u3.w));
    }
    for (; i < e; i += 2) {
        int s = csr[i + half];
        uint4 u = base[(size_t)s * 32 + hl];
        a0 += bflo(u.x); a1 += bfhi(u.x); a2 += bflo(u.y); a3 += bfhi(u.y);
        a4 += bflo(u.z); a5 += bfhi(u.z); a6 += bflo(u.w); a7 += bfhi(u.w);
    }
    a0 += __shfl_xor(a0, 32); a1 += __shfl_xor(a1, 32);
    a2 += __shfl_xor(a2, 32); a3 += __shfl_xor(a3, 32);
    a4 += __shfl_xor(a4, 32); a5 += __shfl_xor(a5, 32);
    a6 += __shfl_xor(a6, 32); a7 += __shfl_xor(a7, 32);
    if (half == 0) {
        float dd = dis[w];
        uint4 o;
        o.x = (unsigned)f2bf(a0 * dd) | ((unsigned)f2bf(a1 * dd) << 16);
        o.y = (unsigned)f2bf(a2 * dd) | ((unsigned)f2bf(a3 * dd) << 16);
        o.z = (unsigned)f2bf(a4 * dd) | ((unsigned)f2bf(a5 * dd) << 16);
        o.w = (unsigned)f2bf(a6 * dd) | ((unsigned)f2bf(a7 * dd) << 16);
        ((uint4*)aggx)[(size_t)w * 32 + hl] = o;
    }
}

// ---- GEMM1: feat1 = dropout(prelu(aggx @ W1 + b1)) -> bf16 ----------------
// LDS-staged (R7 structure — measured best; direct-global (R9) and megafusion
// (R11) variants both regressed). BK=64: 4 K-iters.

__global__ __launch_bounds__(256) void gemm1_kernel(const u16* __restrict__ A,
        const u16* __restrict__ Bt, const float* __restrict__ bias,
        const float* __restrict__ a_p, const u64* __restrict__ mbits,
        u16* __restrict__ out, int M) {
    const int K = IN_DIM;
    __shared__ __align__(16) u16 As[BM * LDT];
    __shared__ __align__(16) u16 Bs[BM * LDT];
    int tid = threadIdx.x;
    int wave = tid >> 6, lane = tid & 63;
    int quad = lane >> 4, l16 = lane & 15;
    int wm = wave & 1, wn = wave >> 1;
    int m0 = blockIdx.x * BM, n0 = blockIdx.y * BM;

    floatx4 acc[4][4];
#pragma unroll
    for (int i = 0; i < 4; i++)
#pragma unroll
        for (int j = 0; j < 4; j++) acc[i][j] = (floatx4){0.f, 0.f, 0.f, 0.f};

    for (int k0 = 0; k0 < K; k0 += BKK) {
        __syncthreads();
#pragma unroll
        for (int u = tid; u < 1024; u += 256) {   // 128 rows x 8 uint4 per matrix
            int row = u >> 3, seg = u & 7;
            uint4 av = make_uint4(0, 0, 0, 0);
            int gr = m0 + row;
            if (gr < M) av = *(const uint4*)&A[(size_t)gr * K + k0 + seg * 8];
            *(uint4*)&As[row * LDT + seg * 8] = av;
            uint4 bv = *(const uint4*)&Bt[(size_t)(n0 + row) * K + k0 + seg * 8];
            *(uint4*)&Bs[row * LDT + seg * 8] = bv;
        }
        __syncthreads();
        short8 bf8[4][2];
#pragma unroll
        for (int i = 0; i < 4; i++)
#pragma unroll
            for (int ks = 0; ks < 2; ks++)
                bf8[i][ks] = *(const short8*)&Bs[(wn * 64 + i * 16 + l16) * LDT + ks * 32 + quad * 8];
#pragma unroll
        for (int mt = 0; mt < 4; mt++) {
            short8 af0 = *(const short8*)&As[(wm * 64 + mt * 16 + l16) * LDT + quad * 8];
            short8 af1 = *(const short8*)&As[(wm * 64 + mt * 16 + l16) * LDT + 32 + quad * 8];
#pragma unroll
            for (int nt = 0; nt < 4; nt++) {
                acc[mt][nt] = __builtin_amdgcn_mfma_f32_16x16x32_bf16(
                    af0, bf8[nt][0], acc[mt][nt], 0, 0, 0);
                acc[mt][nt] = __builtin_amdgcn_mfma_f32_16x16x32_bf16(
                    af1, bf8[nt][1], acc[mt][nt], 0, 0, 0);
            }
        }
    }

    // stage this block's mask bits (128 rows x 4 u64, stride 5 -> 5KB, alias As)
    u64* mb = (u64*)As;
    __syncthreads();
    for (int u = tid; u < BM * 4; u += 256) {
        int row = u >> 2, j = u & 3;
        int gr = m0 + row;
        u64 val = 0;
        if (gr < M) val = mbits[(size_t)gr * 8 + (n0 >> 8) * 4 + j];
        mb[row * 5 + j] = val;
    }
    __syncthreads();

    float alpha = a_p[0];
#pragma unroll
    for (int mt = 0; mt < 4; mt++) {
#pragma unroll
        for (int r = 0; r < 4; r++) {
            int lr = wm * 64 + mt * 16 + quad * 4 + r;   // local row in [0,128)
            int row = m0 + lr;
            if (row >= M) continue;
#pragma unroll
            for (int nt = 0; nt < 4; nt++) {
                int c64 = nt * 16 + l16;                 // col within wn's 64-col half
                int col = n0 + wn * 64 + c64;
                float v = acc[mt][nt][r] + bias[col];
                v = (v >= 0.f) ? v : alpha * v;
                u64 w = mb[lr * 5 + (l16 & 3)];          // j = col & 3 == l16 & 3
                int bit = ((n0 >> 2) + wn * 16 + nt * 4 + (l16 >> 2)) & 63;  // (col>>2)&63
                v = ((w >> bit) & 1ull) ? v * 2.0f : 0.0f;
                out[(size_t)row * H1 + col] = f2bf(v);
            }
        }
    }
}

// ---- GEMM2: ts = bf16( dis[row] * (feat1 @ W2) ) --------------------------
// LDS-staged (R7 structure). 64-row tiles.

__global__ __launch_bounds__(256) void gemm2_kernel(const u16* __restrict__ A,
        const u16* __restrict__ Bt, const float* __restrict__ dis,
        u16* __restrict__ out, int M) {
    const int K = H1;
    __shared__ __align__(16) u16 As[64 * LDT];
    __shared__ __align__(16) u16 Bs[128 * LDT];
    int tid = threadIdx.x;
    int wave = tid >> 6, lane = tid & 63;
    int quad = lane >> 4, l16 = lane & 15;
    int wm = wave & 1, wn = wave >> 1;
    int m0 = blockIdx.x * 64;

    floatx4 acc[2][4];
#pragma unroll
    for (int i = 0; i < 2; i++)
#pragma unroll
        for (int j = 0; j < 4; j++) acc[i][j] = (floatx4){0.f, 0.f, 0.f, 0.f};

    for (int k0 = 0; k0 < K; k0 += BKK) {
        __syncthreads();
#pragma unroll
        for (int u = tid; u < 1536; u += 256) {   // 512 A-chunks + 1024 B-chunks
            if (u < 512) {
                int row = u >> 3, seg = u & 7;
                uint4 av = make_uint4(0, 0, 0, 0);
                int gr = m0 + row;
                if (gr < M) av = *(const uint4*)&A[(size_t)gr * K + k0 + seg * 8];
                *(uint4*)&As[row * LDT + seg * 8] = av;
            } else {
                int v2 = u - 512;
                int row = v2 >> 3, seg = v2 & 7;
                uint4 bv = *(const uint4*)&Bt[(size_t)row * K + k0 + seg * 8];
                *(uint4*)&Bs[row * LDT + seg * 8] = bv;
            }
        }
        __syncthreads();
        short8 bf8[4][2];
#pragma unroll
        for (int i = 0; i < 4; i++)
#pragma unroll
            for (int ks = 0; ks < 2; ks++)
                bf8[i][ks] = *(const short8*)&Bs[(wn * 64 + i * 16 + l16) * LDT + ks * 32 + quad * 8];
#pragma unroll
        for (int mt = 0; mt < 2; mt++) {
            short8 af0 = *(const short8*)&As[(wm * 32 + mt * 16 + l16) * LDT + quad * 8];
            short8 af1 = *(const short8*)&As[(wm * 32 + mt * 16 + l16) * LDT + 32 + quad * 8];
#pragma unroll
            for (int nt = 0; nt < 4; nt++) {
                acc[mt][nt] = __builtin_amdgcn_mfma_f32_16x16x32_bf16(
                    af0, bf8[nt][0], acc[mt][nt], 0, 0, 0);
                acc[mt][nt] = __builtin_amdgcn_mfma_f32_16x16x32_bf16(
                    af1, bf8[nt][1], acc[mt][nt], 0, 0, 0);
            }
        }
    }

#pragma unroll
    for (int mt = 0; mt < 2; mt++) {
#pragma unroll
        for (int r = 0; r < 4; r++) {
            int row = m0 + wm * 32 + mt * 16 + quad * 4 + r;
            if (row >= M) continue;
            float dd = dis[row];
#pragma unroll
            for (int nt = 0; nt < 4; nt++) {
                int col = wn * 64 + nt * 16 + l16;
                out[(size_t)row * H2 + col] = f2bf(acc[mt][nt][r] * dd);
            }
        }
    }
}

// ---- aggregation 2 + epilogue: out = dropout(prelu(dis[d]*(ts[d]+sum ts[s]) + b2)) --
// Dual-row gather (uint2, 8B/lane), padded-even CSR, float4 epilogue.

__global__ __launch_bounds__(256) void agg2_kernel(const u16* __restrict__ ts,
        const int* __restrict__ row_start, const int* __restrict__ csr,
        const float* __restrict__ dis, const float* __restrict__ b2,
        const float* __restrict__ a_p, const int* __restrict__ mask,
        float* __restrict__ out, int n) {
    int gid = blockIdx.x * blockDim.x + threadIdx.x;
    int w = gid >> 6, lane = gid & 63;
    if (w >= n) return;
    const uint2* base = (const uint2*)ts;   // 32 uint2 per 128-feat row
    int half = lane >> 5, hl = lane & 31;
    float a0 = 0.f, a1 = 0.f, a2 = 0.f, a3 = 0.f;
    if (half == 0) {                        // self-loop seed
        uint2 u = base[(size_t)w * 32 + hl];
        a0 = bflo(u.x); a1 = bfhi(u.x); a2 = bflo(u.y); a3 = bfhi(u.y);
    }
    int b = row_start[w], e = row_start[w + 1];
    int i = b;
    for (; i + 8 <= e; i += 8) {
        int s0 = csr[i + half],     s1 = csr[i + 2 + half];
        int s2 = csr[i + 4 + half], s3 = csr[i + 6 + half];
        uint2 u0 = base[(size_t)s0 * 32 + hl];
        uint2 u1 = base[(size_t)s1 * 32 + hl];
        uint2 u2 = base[(size_t)s2 * 32 + hl];
        uint2 u3 = base[(size_t)s3 * 32 + hl];
        a0 += (bflo(u0.x) + bflo(u1.x)) + (bflo(u2.x) + bflo(u3.x));
        a1 += (bfhi(u0.x) + bfhi(u1.x)) + (bfhi(u2.x) + bfhi(u3.x));
        a2 += (bflo(u0.y) + bflo(u1.y)) + (bflo(u2.y) + bflo(u3.y));
        a3 += (bfhi(u0.y) + bfhi(u1.y)) + (bfhi(u2.y) + bfhi(u3.y));
    }
    for (; i < e; i += 2) {
        int s = csr[i + half];
        uint2 u = base[(size_t)s * 32 + hl];
        a0 += bflo(u.x); a1 += bfhi(u.x); a2 += bflo(u.y); a3 += bfhi(u.y);
    }
    a0 += __shfl_xor(a0, 32); a1 += __shfl_xor(a1, 32);
    a2 += __shfl_xor(a2, 32); a3 += __shfl_xor(a3, 32);
    if (half == 0) {
        float dd = dis[w];
        float alpha = a_p[0];
        float4 bb = ((const float4*)b2)[hl];
        float v0 = dd * a0 + bb.x;
        float v1 = dd * a1 + bb.y;
        float v2 = dd * a2 + bb.z;
        float v3 = dd * a3 + bb.w;
        v0 = (v0 >= 0.f) ? v0 : alpha * v0;
        v1 = (v1 >= 0.f) ? v1 : alpha * v1;
        v2 = (v2 >= 0.f) ? v2 : alpha * v2;
        v3 = (v3 >= 0.f) ? v3 : alpha * v3;
        int4 m = ((const int4*)mask)[(size_t)w * 32 + hl];
        v0 = m.x ? v0 * 2.f : 0.f;
        v1 = m.y ? v1 * 2.f : 0.f;
        v2 = m.z ? v2 * 2.f : 0.f;
        v3 = m.w ? v3 * 2.f : 0.f;
        ((float4*)out)[(size_t)w * 32 + hl] = make_float4(v0, v1, v2, v3);
    }
}

// ---- launch ---------------------------------------------------------------

extern "C" void kernel_launch(void* const* d_in, const int* in_sizes, int n_in,
                              void* d_out, int out_size, void* d_ws, size_t ws_size,
                              hipStream_t stream) {
    const float* x  = (const float*)d_in[0];
    const int* ei   = (const int*)d_in[1];
    const float* W1 = (const float*)d_in[2];
    const float* b1 = (const float*)d_in[3];
    const float* W2 = (const float*)d_in[4];
    const float* b2 = (const float*)d_in[5];
    const float* ap = (const float*)d_in[6];
    const int* mask1 = (const int*)d_in[7];
    const int* mask2 = (const int*)d_in[8];

    int n = in_sizes[0] / IN_DIM;      // 50000
    int E = in_sizes[1] / 2;           // 400000
    const int* srcA = ei;
    const int* dstA = ei + E;

    // ws layout (aliased lifetimes):
    //   feat1 (n*H1 bf16); first half doubles as xs (n+1 rows incl. sentinel)
    //   ts ((n+1)*H2 bf16; doubles as mask1 bitpack before gemm2 writes ts),
    //   w1t, w2t, dis, counts, cursor, row_start, csr (E + n pad), partials
    // aggx (n*IN_DIM bf16) lives in d_out (dead before agg2 rewrites d_out).
    char* p = (char*)d_ws;
    auto alloc = [&](size_t bytes) {
        char* r = p;
        p += (bytes + 255) & ~(size_t)255;
        return r;
    };
    u16* feat1     = (u16*)alloc((size_t)n * H1 * 2);
    u16* xs        = feat1;            // alias: xs dead before feat1 is written
    u16* ts        = (u16*)alloc((size_t)(n + 1) * H2 * 2);
    u64* bits1     = (u64*)ts;         // alias: bits1 (3.2MB) dead before gemm2 writes ts
    u16* w1t       = (u16*)alloc((size_t)IN_DIM * H1 * 2);
    u16* w2t       = (u16*)alloc((size_t)H1 * H2 * 2);
    float* dis     = (float*)alloc((size_t)n * 4);
    int* counts    = (int*)alloc((size_t)n * 4);
    int* cursor    = (int*)alloc((size_t)n * 4);
    int* row_start = (int*)alloc(((size_t)n + 1) * 4);
    int* csr       = (int*)alloc(((size_t)E + n + 64) * 4);
    int nscan = (n + SCAN_CHUNK - 1) / SCAN_CHUNK;
    int* partials  = (int*)alloc(((size_t)nscan + 1) * 4);
    u16* aggx      = (u16*)d_out;      // n*IN_DIM*2 == out_size*4 bytes exactly
    if ((size_t)(p - (char*)d_ws) > ws_size) return;  // ws too small: leave zeros

    const int tpb = 256;
    int total4 = n * H1 / 4;           // int4 elements; divisible by 256
    int PB = (total4 + tpb - 1) / tpb;
    int HB = (E + tpb - 1) / tpb;
    int T1B = (IN_DIM * H1 + tpb - 1) / tpb;
    int T2B = (H1 * H2 + tpb - 1) / tpb;
    hipMemsetAsync(counts, 0, (size_t)n * 4, stream);
    prep_kernel<<<PB + HB + T1B + T2B, tpb, 0, stream>>>((const int4*)mask1, bits1, total4,
        dstA, counts, E, n, W1, w1t, W2, w2t, PB, HB, T1B);
    partial_sum_kernel<<<nscan, tpb, 0, stream>>>(counts, partials, n);
    scan_partials_kernel<<<1, 64, 0, stream>>>(partials, nscan,
        (unsigned*)(ts + (size_t)n * H2));
    scan_emit_kernel<<<nscan, tpb, 0, stream>>>(counts, partials, row_start, cursor, dis,
                                                csr, n, nscan);
    scatter_kernel<<<(E + tpb - 1) / tpb, tpb, 0, stream>>>(srcA, dstA, cursor, csr, E, n);
    scale_cast_kernel<<<(((n + 1) * (IN_DIM / 4)) + tpb - 1) / tpb, tpb, 0, stream>>>(x, dis, xs, n);
    agg1_kernel<<<(n * 64 + tpb - 1) / tpb, tpb, 0, stream>>>(xs, row_start, csr, dis, aggx, n);
    dim3 g1((n + BM - 1) / BM, H1 / BM);
    gemm1_kernel<<<g1, tpb, 0, stream>>>(aggx, w1t, b1, ap, bits1, feat1, n);
    dim3 g2((n + 63) / 64, 1);
    gemm2_kernel<<<g2, tpb, 0, stream>>>(feat1, w2t, dis, ts, n);
    agg2_kernel<<<(n * 64 + tpb - 1) / tpb, tpb, 0, stream>>>(ts, row_start, csr, dis, b2, ap,
                                                              mask2, (float*)d_out, n);
}

// Round 13
// 399.027 us; speedup vs baseline: 1.0949x; 1.0236x over previous
//
#include <hip/hip_runtime.h>
#include <hip/hip_bf16.h>

#define IN_DIM 256
#define H1 512
#define H2 128
#define BM 128
#define BKK 64   // K-tile depth: 4 K-iters for gemm1, 8 for gemm2
#define LDT 72   // LDS row stride (shorts) for gemm2's 64-short rows (+8 pad)
#define SCAN_CHUNK 4096  // 256 threads x 16 elements

typedef unsigned short u16;
typedef unsigned long long u64;
typedef __attribute__((ext_vector_type(8))) short short8;
typedef __attribute__((ext_vector_type(4))) float floatx4;

__device__ __forceinline__ u16 f2bf(float f) {
    union { float f; unsigned u; } c; c.f = f;
    unsigned u = c.u;
    return (u16)((u + 0x7fffu + ((u >> 16) & 1u)) >> 16);
}
__device__ __forceinline__ float bflo(unsigned w) {
    union { unsigned u; float f; } c; c.u = w << 16; return c.f;
}
__device__ __forceinline__ float bfhi(unsigned w) {
    union { unsigned u; float f; } c; c.u = w & 0xffff0000u; return c.f;
}

// 16B-per-lane DMA: global -> LDS, dest = wave-uniform base + lane*16
__device__ __forceinline__ void gl_lds16(const u16* g, u16* l) {
    __builtin_amdgcn_global_load_lds(
        (const __attribute__((address_space(1))) void*)g,
        (__attribute__((address_space(3))) void*)l, 16, 0, 0);
}

// ---- fused prep: mask1 bit-pack + degree histogram + W1/W2 transpose-cast --
// pack layout: bit i of word [g*4+j] = mask[g*256 + 4*i + j]  (g = wave index).

__global__ __launch_bounds__(256) void prep_kernel(const int4* __restrict__ mask4,
        u64* __restrict__ bits, int total4,
        const int* __restrict__ dstA, int* __restrict__ counts, int E, int n,
        const float* __restrict__ W1, u16* __restrict__ w1t,
        const float* __restrict__ W2, u16* __restrict__ w2t,
        int PB, int HB, int T1B) {
    int b = blockIdx.x;
    if (b < PB) {                    // ---- pack mask1
        int gid = b * 256 + threadIdx.x;
        int lane = threadIdx.x & 63;
        int4 v = (gid < total4) ? mask4[gid] : make_int4(0, 0, 0, 0);
        u64 b0 = __ballot(v.x != 0);
        u64 b1 = __ballot(v.y != 0);
        u64 b2 = __ballot(v.z != 0);
        u64 b3 = __ballot(v.w != 0);
        u64 sel = (lane == 0) ? b0 : (lane == 1) ? b1 : (lane == 2) ? b2 : b3;
        if (lane < 4 && gid < total4)
            bits[(size_t)(gid >> 6) * 4 + lane] = sel;
    } else if (b < PB + HB) {        // ---- histogram of dst degrees
        int e = (b - PB) * 256 + threadIdx.x;
        if (e < E) {
            int d = dstA[e];
            if ((unsigned)d < (unsigned)n) atomicAdd(&counts[d], 1);
        }
    } else if (b < PB + HB + T1B) {  // ---- W1^T cast (256x512 -> 512x256)
        int idx = (b - PB - HB) * 256 + threadIdx.x;
        if (idx < IN_DIM * H1) {
            int k = idx >> 9, c = idx & (H1 - 1);
            w1t[c * IN_DIM + k] = f2bf(W1[idx]);
        }
    } else {                         // ---- W2^T cast (512x128 -> 128x512)
        int idx = (b - PB - HB - T1B) * 256 + threadIdx.x;
        if (idx < H1 * H2) {
            int k = idx >> 7, c = idx & (H2 - 1);
            w2t[c * H1 + k] = f2bf(W2[idx]);
        }
    }
}

// ---- 3-dispatch hierarchical scan over EVEN-CEILED counts -----------------
// pads every adjacency list to even length; the pad slot holds sentinel index n
// (a zero row in xs/ts) so the dual-row agg loops need no remainder handling.

__global__ __launch_bounds__(256) void partial_sum_kernel(const int* __restrict__ counts,
        int* __restrict__ partials, int n) {
    int t = threadIdx.x;
    int base = blockIdx.x * SCAN_CHUNK + t * 16;
    int s = 0;
    int m = (base < n) ? min(16, n - base) : 0;
    for (int i = 0; i < m; ++i) s += (counts[base + i] + 1) & ~1;
    __shared__ int red[256];
    red[t] = s;
    __syncthreads();
    for (int off = 128; off > 0; off >>= 1) {
        if (t < off) red[t] += red[t + off];
        __syncthreads();
    }
    if (t == 0) partials[blockIdx.x] = red[0];
}

// also zeroes the sentinel row n of ts while this tiny kernel is here
__global__ void scan_partials_kernel(int* __restrict__ partials, int nb,
                                     unsigned* __restrict__ ts_zero_row) {
    int t = threadIdx.x;
    if (t < 64) ts_zero_row[t] = 0;   // ts row n: 128 bf16 = 64 uints
    if (t == 0 && blockIdx.x == 0) {
        int run = 0;
        for (int i = 0; i < nb; ++i) { int c = partials[i]; partials[i] = run; run += c; }
        partials[nb] = run;   // total (padded)
    }
}

__global__ __launch_bounds__(256) void scan_emit_kernel(const int* __restrict__ counts,
        const int* __restrict__ partials, int* __restrict__ row_start,
        int* __restrict__ cursor, float* __restrict__ dis,
        int* __restrict__ csr, int n, int nb) {
    int t = threadIdx.x;
    int base = blockIdx.x * SCAN_CHUNK + t * 16;
    int cnt[16];
    int s = 0;
    int m = (base < n) ? min(16, n - base) : 0;
    for (int i = 0; i < m; ++i) { cnt[i] = counts[base + i]; s += (cnt[i] + 1) & ~1; }
    __shared__ int red[256];
    red[t] = s;
    __syncthreads();
    for (int off = 1; off < 256; off <<= 1) {   // inclusive Hillis-Steele
        int v = red[t];
        int vo = (t >= off) ? red[t - off] : 0;
        __syncthreads();
        red[t] = v + vo;
        __syncthreads();
    }
    int run = partials[blockIdx.x] + (t ? red[t - 1] : 0);
    for (int i = 0; i < m; ++i) {
        int c = cnt[i];
        row_start[base + i] = run;
        cursor[base + i] = run;
        dis[base + i] = rsqrtf((float)(c + 1));   // deg = REAL indeg + self-loop
        if (c & 1) csr[run + c] = n;              // pad slot -> sentinel zero row
        run += (c + 1) & ~1;
    }
    if (blockIdx.x == 0 && t == 0) row_start[n] = partials[nb];
}

__global__ void scatter_kernel(const int* __restrict__ srcA, const int* __restrict__ dstA,
                               int* __restrict__ cursor, int* __restrict__ csr,
                               int E, int n) {
    int e = blockIdx.x * blockDim.x + threadIdx.x;
    if (e < E) {
        int d = dstA[e];
        int s = srcA[e];
        if ((unsigned)d < (unsigned)n && (unsigned)s < (unsigned)n) {
            int p = atomicAdd(&cursor[d], 1);
            csr[p] = s;
        }
    }
}

// xs[i,:] = bf16(dis[i] * x[i,:]) for i<n;  xs[n,:] = 0 (sentinel row)
__global__ void scale_cast_kernel(const float* __restrict__ x, const float* __restrict__ dis,
                                  u16* __restrict__ xs, int n) {
    int gid = blockIdx.x * blockDim.x + threadIdx.x;
    int total = (n + 1) * (IN_DIM / 4);
    if (gid >= total) return;
    int node = gid >> 6;   // IN_DIM/4 == 64
    uint2 o = make_uint2(0, 0);
    if (node < n) {
        float4 v = ((const float4*)x)[gid];
        float d = dis[node];
        o.x = (unsigned)f2bf(v.x * d) | ((unsigned)f2bf(v.y * d) << 16);
        o.y = (unsigned)f2bf(v.z * d) | ((unsigned)f2bf(v.w * d) << 16);
    }
    ((uint2*)xs)[gid] = o;
}

// ---- aggregation 1: aggx[d] = bf16( dis[d] * (xs[d] + sum_{s in in(d)} xs[s]) ) -----
// Dual-row gather: lower/upper 32 lanes take rows j / j+1 at 16B/lane (uint4).

__global__ __launch_bounds__(256) void agg1_kernel(const u16* __restrict__ xs,
        const int* __restrict__ row_start, const int* __restrict__ csr,
        const float* __restrict__ dis, u16* __restrict__ aggx, int n) {
    int gid = blockIdx.x * blockDim.x + threadIdx.x;
    int w = gid >> 6, lane = gid & 63;
    if (w >= n) return;
    const uint4* base = (const uint4*)xs;       // 32 uint4 per 256-feat row
    int half = lane >> 5, hl = lane & 31;
    float a0 = 0.f, a1 = 0.f, a2 = 0.f, a3 = 0.f, a4 = 0.f, a5 = 0.f, a6 = 0.f, a7 = 0.f;
    if (half == 0) {                            // self-loop seed in lower half only
        uint4 u = base[(size_t)w * 32 + hl];
        a0 = bflo(u.x); a1 = bfhi(u.x); a2 = bflo(u.y); a3 = bfhi(u.y);
        a4 = bflo(u.z); a5 = bfhi(u.z); a6 = bflo(u.w); a7 = bfhi(u.w);
    }
    int b = row_start[w], e = row_start[w + 1];
    int i = b;
    for (; i + 8 <= e; i += 8) {
        int s0 = csr[i + half],     s1 = csr[i + 2 + half];
        int s2 = csr[i + 4 + half], s3 = csr[i + 6 + half];
        uint4 u0 = base[(size_t)s0 * 32 + hl];
        uint4 u1 = base[(size_t)s1 * 32 + hl];
        uint4 u2 = base[(size_t)s2 * 32 + hl];
        uint4 u3 = base[(size_t)s3 * 32 + hl];
        a0 += (bflo(u0.x) + bflo(u1.x)) + (bflo(u2.x) + bflo(u3.x));
        a1 += (bfhi(u0.x) + bfhi(u1.x)) + (bfhi(u2.x) + bfhi(u3.x));
        a2 += (bflo(u0.y) + bflo(u1.y)) + (bflo(u2.y) + bflo(u3.y));
        a3 += (bfhi(u0.y) + bfhi(u1.y)) + (bfhi(u2.y) + bfhi(u3.y));
        a4 += (bflo(u0.z) + bflo(u1.z)) + (bflo(u2.z) + bflo(u3.z));
        a5 += (bfhi(u0.z) + bfhi(u1.z)) + (bfhi(u2.z) + bfhi(u3.z));
        a6 += (bflo(u0.w) + bflo(u1.w)) + (bflo(u2.w) + bflo(u3.w));
        a7 += (bfhi(u0.w) + bfhi(u1.w)) + (bfhi(u2.w) + bfhi(u3.w));
    }
    for (; i < e; i += 2) {
        int s = csr[i + half];
        uint4 u = base[(size_t)s * 32 + hl];
        a0 += bflo(u.x); a1 += bfhi(u.x); a2 += bflo(u.y); a3 += bfhi(u.y);
        a4 += bflo(u.z); a5 += bfhi(u.z); a6 += bflo(u.w); a7 += bfhi(u.w);
    }
    a0 += __shfl_xor(a0, 32); a1 += __shfl_xor(a1, 32);
    a2 += __shfl_xor(a2, 32); a3 += __shfl_xor(a3, 32);
    a4 += __shfl_xor(a4, 32); a5 += __shfl_xor(a5, 32);
    a6 += __shfl_xor(a6, 32); a7 += __shfl_xor(a7, 32);
    if (half == 0) {
        float dd = dis[w];
        uint4 o;
        o.x = (unsigned)f2bf(a0 * dd) | ((unsigned)f2bf(a1 * dd) << 16);
        o.y = (unsigned)f2bf(a2 * dd) | ((unsigned)f2bf(a3 * dd) << 16);
        o.z = (unsigned)f2bf(a4 * dd) | ((unsigned)f2bf(a5 * dd) << 16);
        o.w = (unsigned)f2bf(a6 * dd) | ((unsigned)f2bf(a7 * dd) << 16);
        ((uint4*)aggx)[(size_t)w * 32 + hl] = o;
    }
}

// ---- GEMM1: feat1 = dropout(prelu(aggx @ W1 + b1)) -> bf16 ----------------
// DMA staging: global_load_lds width=16 (no VGPR round-trip, no ds_writes),
// unpadded 64-short LDS rows with XOR seg swizzle (seg' = seg ^ (row&7)) so
// fragment ds_read_b128s stay 2-way (free). MFMA order identical to R7/R12.

__global__ __launch_bounds__(256) void gemm1_kernel(const u16* __restrict__ A,
        const u16* __restrict__ Bt, const float* __restrict__ bias,
        const float* __restrict__ a_p, const u64* __restrict__ mbits,
        u16* __restrict__ out, int M) {
    const int K = IN_DIM;
    __shared__ __align__(16) u16 As[BM * 64];   // 16 KB, unpadded
    __shared__ __align__(16) u16 Bs[BM * 64];   // 16 KB
    int tid = threadIdx.x;
    int wave = tid >> 6, lane = tid & 63;
    int quad = lane >> 4, l16 = lane & 15;
    int wm = wave & 1, wn = wave >> 1;
    int m0 = blockIdx.x * BM, n0 = blockIdx.y * BM;

    // DMA lane roles: chunk = 8 rows x 128B; lane -> (row r8, seg), XOR swizzle
    int r8 = lane >> 3, seg = lane & 7;
    int segx = seg ^ r8;                        // global seg fetched by this lane
    int l7 = l16 & 7;                           // row&7 for fragment reads

    floatx4 acc[4][4];
#pragma unroll
    for (int i = 0; i < 4; i++)
#pragma unroll
        for (int j = 0; j < 4; j++) acc[i][j] = (floatx4){0.f, 0.f, 0.f, 0.f};

    for (int k0 = 0; k0 < K; k0 += BKK) {
        __syncthreads();                        // prev-iter fragment reads done
#pragma unroll
        for (int c = 0; c < 4; c++) {
            int rl = (wave * 4 + c) * 8 + r8;   // local row 0..127
            int gra = m0 + rl; if (gra >= M) gra = M - 1;  // clamp: rows >=M discarded in epilogue
            gl_lds16(A  + (size_t)gra * K        + k0 + segx * 8, &As[(wave * 4 + c) * 512]);
            gl_lds16(Bt + (size_t)(n0 + rl) * K  + k0 + segx * 8, &Bs[(wave * 4 + c) * 512]);
        }
        __syncthreads();                        // vmcnt drain: tiles visible
        short8 bf8[4][2];
#pragma unroll
        for (int i = 0; i < 4; i++)
#pragma unroll
            for (int ks = 0; ks < 2; ks++)
                bf8[i][ks] = *(const short8*)&Bs[(wn * 64 + i * 16 + l16) * 64
                                                 + (((ks * 4 + quad) ^ l7) * 8)];
#pragma unroll
        for (int mt = 0; mt < 4; mt++) {
            short8 af0 = *(const short8*)&As[(wm * 64 + mt * 16 + l16) * 64 + ((quad ^ l7) * 8)];
            short8 af1 = *(const short8*)&As[(wm * 64 + mt * 16 + l16) * 64 + (((4 + quad) ^ l7) * 8)];
#pragma unroll
            for (int nt = 0; nt < 4; nt++) {
                acc[mt][nt] = __builtin_amdgcn_mfma_f32_16x16x32_bf16(
                    af0, bf8[nt][0], acc[mt][nt], 0, 0, 0);
                acc[mt][nt] = __builtin_amdgcn_mfma_f32_16x16x32_bf16(
                    af1, bf8[nt][1], acc[mt][nt], 0, 0, 0);
            }
        }
    }

    // stage this block's mask bits (128 rows x 4 u64, stride 5 -> 5KB, alias As)
    u64* mb = (u64*)As;
    __syncthreads();
    for (int u = tid; u < BM * 4; u += 256) {
        int row = u >> 2, j = u & 3;
        int gr = m0 + row;
        u64 val = 0;
        if (gr < M) val = mbits[(size_t)gr * 8 + (n0 >> 8) * 4 + j];
        mb[row * 5 + j] = val;
    }
    __syncthreads();

    float alpha = a_p[0];
#pragma unroll
    for (int mt = 0; mt < 4; mt++) {
#pragma unroll
        for (int r = 0; r < 4; r++) {
            int lr = wm * 64 + mt * 16 + quad * 4 + r;   // local row in [0,128)
            int row = m0 + lr;
            if (row >= M) continue;
#pragma unroll
            for (int nt = 0; nt < 4; nt++) {
                int c64 = nt * 16 + l16;                 // col within wn's 64-col half
                int col = n0 + wn * 64 + c64;
                float v = acc[mt][nt][r] + bias[col];
                v = (v >= 0.f) ? v : alpha * v;
                u64 w = mb[lr * 5 + (l16 & 3)];          // j = col & 3 == l16 & 3
                int bit = ((n0 >> 2) + wn * 16 + nt * 4 + (l16 >> 2)) & 63;  // (col>>2)&63
                v = ((w >> bit) & 1ull) ? v * 2.0f : 0.0f;
                out[(size_t)row * H1 + col] = f2bf(v);
            }
        }
    }
}

// ---- GEMM2: ts = bf16( dis[row] * (feat1 @ W2) ) --------------------------
// LDS-staged (R7 structure, unchanged this round). 64-row tiles.

__global__ __launch_bounds__(256) void gemm2_kernel(const u16* __restrict__ A,
        const u16* __restrict__ Bt, const float* __restrict__ dis,
        u16* __restrict__ out, int M) {
    const int K = H1;
    __shared__ __align__(16) u16 As[64 * LDT];
    __shared__ __align__(16) u16 Bs[128 * LDT];
    int tid = threadIdx.x;
    int wave = tid >> 6, lane = tid & 63;
    int quad = lane >> 4, l16 = lane & 15;
    int wm = wave & 1, wn = wave >> 1;
    int m0 = blockIdx.x * 64;

    floatx4 acc[2][4];
#pragma unroll
    for (int i = 0; i < 2; i++)
#pragma unroll
        for (int j = 0; j < 4; j++) acc[i][j] = (floatx4){0.f, 0.f, 0.f, 0.f};

    for (int k0 = 0; k0 < K; k0 += BKK) {
        __syncthreads();
#pragma unroll
        for (int u = tid; u < 1536; u += 256) {   // 512 A-chunks + 1024 B-chunks
            if (u < 512) {
                int row = u >> 3, seg = u & 7;
                uint4 av = make_uint4(0, 0, 0, 0);
                int gr = m0 + row;
                if (gr < M) av = *(const uint4*)&A[(size_t)gr * K + k0 + seg * 8];
                *(uint4*)&As[row * LDT + seg * 8] = av;
            } else {
                int v2 = u - 512;
                int row = v2 >> 3, seg = v2 & 7;
                uint4 bv = *(const uint4*)&Bt[(size_t)row * K + k0 + seg * 8];
                *(uint4*)&Bs[row * LDT + seg * 8] = bv;
            }
        }
        __syncthreads();
        short8 bf8[4][2];
#pragma unroll
        for (int i = 0; i < 4; i++)
#pragma unroll
            for (int ks = 0; ks < 2; ks++)
                bf8[i][ks] = *(const short8*)&Bs[(wn * 64 + i * 16 + l16) * LDT + ks * 32 + quad * 8];
#pragma unroll
        for (int mt = 0; mt < 2; mt++) {
            short8 af0 = *(const short8*)&As[(wm * 32 + mt * 16 + l16) * LDT + quad * 8];
            short8 af1 = *(const short8*)&As[(wm * 32 + mt * 16 + l16) * LDT + 32 + quad * 8];
#pragma unroll
            for (int nt = 0; nt < 4; nt++) {
                acc[mt][nt] = __builtin_amdgcn_mfma_f32_16x16x32_bf16(
                    af0, bf8[nt][0], acc[mt][nt], 0, 0, 0);
                acc[mt][nt] = __builtin_amdgcn_mfma_f32_16x16x32_bf16(
                    af1, bf8[nt][1], acc[mt][nt], 0, 0, 0);
            }
        }
    }

#pragma unroll
    for (int mt = 0; mt < 2; mt++) {
#pragma unroll
        for (int r = 0; r < 4; r++) {
            int row = m0 + wm * 32 + mt * 16 + quad * 4 + r;
            if (row >= M) continue;
            float dd = dis[row];
#pragma unroll
            for (int nt = 0; nt < 4; nt++) {
                int col = wn * 64 + nt * 16 + l16;
                out[(size_t)row * H2 + col] = f2bf(acc[mt][nt][r] * dd);
            }
        }
    }
}

// ---- aggregation 2 + epilogue: out = dropout(prelu(dis[d]*(ts[d]+sum ts[s]) + b2)) --
// Dual-row gather (uint2, 8B/lane), padded-even CSR, float4 epilogue.

__global__ __launch_bounds__(256) void agg2_kernel(const u16* __restrict__ ts,
        const int* __restrict__ row_start, const int* __restrict__ csr,
        const float* __restrict__ dis, const float* __restrict__ b2,
        const float* __restrict__ a_p, const int* __restrict__ mask,
        float* __restrict__ out, int n) {
    int gid = blockIdx.x * blockDim.x + threadIdx.x;
    int w = gid >> 6, lane = gid & 63;
    if (w >= n) return;
    const uint2* base = (const uint2*)ts;   // 32 uint2 per 128-feat row
    int half = lane >> 5, hl = lane & 31;
    float a0 = 0.f, a1 = 0.f, a2 = 0.f, a3 = 0.f;
    if (half == 0) {                        // self-loop seed
        uint2 u = base[(size_t)w * 32 + hl];
        a0 = bflo(u.x); a1 = bfhi(u.x); a2 = bflo(u.y); a3 = bfhi(u.y);
    }
    int b = row_start[w], e = row_start[w + 1];
    int i = b;
    for (; i + 8 <= e; i += 8) {
        int s0 = csr[i + half],     s1 = csr[i + 2 + half];
        int s2 = csr[i + 4 + half], s3 = csr[i + 6 + half];
        uint2 u0 = base[(size_t)s0 * 32 + hl];
        uint2 u1 = base[(size_t)s1 * 32 + hl];
        uint2 u2 = base[(size_t)s2 * 32 + hl];
        uint2 u3 = base[(size_t)s3 * 32 + hl];
        a0 += (bflo(u0.x) + bflo(u1.x)) + (bflo(u2.x) + bflo(u3.x));
        a1 += (bfhi(u0.x) + bfhi(u1.x)) + (bfhi(u2.x) + bfhi(u3.x));
        a2 += (bflo(u0.y) + bflo(u1.y)) + (bflo(u2.y) + bflo(u3.y));
        a3 += (bfhi(u0.y) + bfhi(u1.y)) + (bfhi(u2.y) + bfhi(u3.y));
    }
    for (; i < e; i += 2) {
        int s = csr[i + half];
        uint2 u = base[(size_t)s * 32 + hl];
        a0 += bflo(u.x); a1 += bfhi(u.x); a2 += bflo(u.y); a3 += bfhi(u.y);
    }
    a0 += __shfl_xor(a0, 32); a1 += __shfl_xor(a1, 32);
    a2 += __shfl_xor(a2, 32); a3 += __shfl_xor(a3, 32);
    if (half == 0) {
        float dd = dis[w];
        float alpha = a_p[0];
        float4 bb = ((const float4*)b2)[hl];
        float v0 = dd * a0 + bb.x;
        float v1 = dd * a1 + bb.y;
        float v2 = dd * a2 + bb.z;
        float v3 = dd * a3 + bb.w;
        v0 = (v0 >= 0.f) ? v0 : alpha * v0;
        v1 = (v1 >= 0.f) ? v1 : alpha * v1;
        v2 = (v2 >= 0.f) ? v2 : alpha * v2;
        v3 = (v3 >= 0.f) ? v3 : alpha * v3;
        int4 m = ((const int4*)mask)[(size_t)w * 32 + hl];
        v0 = m.x ? v0 * 2.f : 0.f;
        v1 = m.y ? v1 * 2.f : 0.f;
        v2 = m.z ? v2 * 2.f : 0.f;
        v3 = m.w ? v3 * 2.f : 0.f;
        ((float4*)out)[(size_t)w * 32 + hl] = make_float4(v0, v1, v2, v3);
    }
}

// ---- launch ---------------------------------------------------------------

extern "C" void kernel_launch(void* const* d_in, const int* in_sizes, int n_in,
                              void* d_out, int out_size, void* d_ws, size_t ws_size,
                              hipStream_t stream) {
    const float* x  = (const float*)d_in[0];
    const int* ei   = (const int*)d_in[1];
    const float* W1 = (const float*)d_in[2];
    const float* b1 = (const float*)d_in[3];
    const float* W2 = (const float*)d_in[4];
    const float* b2 = (const float*)d_in[5];
    const float* ap = (const float*)d_in[6];
    const int* mask1 = (const int*)d_in[7];
    const int* mask2 = (const int*)d_in[8];

    int n = in_sizes[0] / IN_DIM;      // 50000
    int E = in_sizes[1] / 2;           // 400000
    const int* srcA = ei;
    const int* dstA = ei + E;

    // ws layout (aliased lifetimes):
    //   feat1 (n*H1 bf16); first half doubles as xs (n+1 rows incl. sentinel)
    //   ts ((n+1)*H2 bf16; doubles as mask1 bitpack before gemm2 writes ts),
    //   w1t, w2t, dis, counts, cursor, row_start, csr (E + n pad), partials
    // aggx (n*IN_DIM bf16) lives in d_out (dead before agg2 rewrites d_out).
    char* p = (char*)d_ws;
    auto alloc = [&](size_t bytes) {
        char* r = p;
        p += (bytes + 255) & ~(size_t)255;
        return r;
    };
    u16* feat1     = (u16*)alloc((size_t)n * H1 * 2);
    u16* xs        = feat1;            // alias: xs dead before feat1 is written
    u16* ts        = (u16*)alloc((size_t)(n + 1) * H2 * 2);
    u64* bits1     = (u64*)ts;         // alias: bits1 (3.2MB) dead before gemm2 writes ts
    u16* w1t       = (u16*)alloc((size_t)IN_DIM * H1 * 2);
    u16* w2t       = (u16*)alloc((size_t)H1 * H2 * 2);
    float* dis     = (float*)alloc((size_t)n * 4);
    int* counts    = (int*)alloc((size_t)n * 4);
    int* cursor    = (int*)alloc((size_t)n * 4);
    int* row_start = (int*)alloc(((size_t)n + 1) * 4);
    int* csr       = (int*)alloc(((size_t)E + n + 64) * 4);
    int nscan = (n + SCAN_CHUNK - 1) / SCAN_CHUNK;
    int* partials  = (int*)alloc(((size_t)nscan + 1) * 4);
    u16* aggx      = (u16*)d_out;      // n*IN_DIM*2 == out_size*4 bytes exactly
    if ((size_t)(p - (char*)d_ws) > ws_size) return;  // ws too small: leave zeros

    const int tpb = 256;
    int total4 = n * H1 / 4;           // int4 elements; divisible by 256
    int PB = (total4 + tpb - 1) / tpb;
    int HB = (E + tpb - 1) / tpb;
    int T1B = (IN_DIM * H1 + tpb - 1) / tpb;
    int T2B = (H1 * H2 + tpb - 1) / tpb;
    hipMemsetAsync(counts, 0, (size_t)n * 4, stream);
    prep_kernel<<<PB + HB + T1B + T2B, tpb, 0, stream>>>((const int4*)mask1, bits1, total4,
        dstA, counts, E, n, W1, w1t, W2, w2t, PB, HB, T1B);
    partial_sum_kernel<<<nscan, tpb, 0, stream>>>(counts, partials, n);
    scan_partials_kernel<<<1, 64, 0, stream>>>(partials, nscan,
        (unsigned*)(ts + (size_t)n * H2));
    scan_emit_kernel<<<nscan, tpb, 0, stream>>>(counts, partials, row_start, cursor, dis,
                                                csr, n, nscan);
    scatter_kernel<<<(E + tpb - 1) / tpb, tpb, 0, stream>>>(srcA, dstA, cursor, csr, E, n);
    scale_cast_kernel<<<(((n + 1) * (IN_DIM / 4)) + tpb - 1) / tpb, tpb, 0, stream>>>(x, dis, xs, n);
    agg1_kernel<<<(n * 64 + tpb - 1) / tpb, tpb, 0, stream>>>(xs, row_start, csr, dis, aggx, n);
    dim3 g1((n + BM - 1) / BM, H1 / BM);
    gemm1_kernel<<<g1, tpb, 0, stream>>>(aggx, w1t, b1, ap, bits1, feat1, n);
    dim3 g2((n + 63) / 64, 1);
    gemm2_kernel<<<g2, tpb, 0, stream>>>(feat1, w2t, dis, ts, n);
    agg2_kernel<<<(n * 64 + tpb - 1) / tpb, tpb, 0, stream>>>(ts, row_start, csr, dis, b2, ap,
                                                              mask2, (float*)d_out, n);
}

// Round 14
// 390.567 us; speedup vs baseline: 1.1186x; 1.0217x over previous
//
#include <hip/hip_runtime.h>
#include <hip/hip_bf16.h>

#define IN_DIM 256
#define H1 512
#define H2 128
#define BM 128
#define BKK 64   // K-tile depth: 4 K-iters for gemm1, 8 for gemm2
#define SCAN_CHUNK 4096  // 256 threads x 16 elements

typedef unsigned short u16;
typedef unsigned long long u64;
typedef __attribute__((ext_vector_type(8))) short short8;
typedef __attribute__((ext_vector_type(4))) float floatx4;

__device__ __forceinline__ u16 f2bf(float f) {
    union { float f; unsigned u; } c; c.f = f;
    unsigned u = c.u;
    return (u16)((u + 0x7fffu + ((u >> 16) & 1u)) >> 16);
}
__device__ __forceinline__ float bflo(unsigned w) {
    union { unsigned u; float f; } c; c.u = w << 16; return c.f;
}
__device__ __forceinline__ float bfhi(unsigned w) {
    union { unsigned u; float f; } c; c.u = w & 0xffff0000u; return c.f;
}

// 16B-per-lane DMA: global -> LDS, dest = wave-uniform base + lane*16
__device__ __forceinline__ void gl_lds16(const u16* g, u16* l) {
    __builtin_amdgcn_global_load_lds(
        (const __attribute__((address_space(1))) void*)g,
        (__attribute__((address_space(3))) void*)l, 16, 0, 0);
}

// ---- fused prep: mask1 bit-pack + degree histogram + W1/W2 transpose-cast --
// pack layout: bit i of word [g*4+j] = mask[g*256 + 4*i + j]  (g = wave index).

__global__ __launch_bounds__(256) void prep_kernel(const int4* __restrict__ mask4,
        u64* __restrict__ bits, int total4,
        const int* __restrict__ dstA, int* __restrict__ counts, int E, int n,
        const float* __restrict__ W1, u16* __restrict__ w1t,
        const float* __restrict__ W2, u16* __restrict__ w2t,
        int PB, int HB, int T1B) {
    int b = blockIdx.x;
    if (b < PB) {                    // ---- pack mask1
        int gid = b * 256 + threadIdx.x;
        int lane = threadIdx.x & 63;
        int4 v = (gid < total4) ? mask4[gid] : make_int4(0, 0, 0, 0);
        u64 b0 = __ballot(v.x != 0);
        u64 b1 = __ballot(v.y != 0);
        u64 b2 = __ballot(v.z != 0);
        u64 b3 = __ballot(v.w != 0);
        u64 sel = (lane == 0) ? b0 : (lane == 1) ? b1 : (lane == 2) ? b2 : b3;
        if (lane < 4 && gid < total4)
            bits[(size_t)(gid >> 6) * 4 + lane] = sel;
    } else if (b < PB + HB) {        // ---- histogram of dst degrees
        int e = (b - PB) * 256 + threadIdx.x;
        if (e < E) {
            int d = dstA[e];
            if ((unsigned)d < (unsigned)n) atomicAdd(&counts[d], 1);
        }
    } else if (b < PB + HB + T1B) {  // ---- W1^T cast (256x512 -> 512x256)
        int idx = (b - PB - HB) * 256 + threadIdx.x;
        if (idx < IN_DIM * H1) {
            int k = idx >> 9, c = idx & (H1 - 1);
            w1t[c * IN_DIM + k] = f2bf(W1[idx]);
        }
    } else {                         // ---- W2^T cast (512x128 -> 128x512)
        int idx = (b - PB - HB - T1B) * 256 + threadIdx.x;
        if (idx < H1 * H2) {
            int k = idx >> 7, c = idx & (H2 - 1);
            w2t[c * H1 + k] = f2bf(W2[idx]);
        }
    }
}

// ---- 3-dispatch hierarchical scan over EVEN-CEILED counts -----------------
// pads every adjacency list to even length; the pad slot holds sentinel index n
// (a zero row in xs/ts) so the dual-row agg loops need no remainder handling.

__global__ __launch_bounds__(256) void partial_sum_kernel(const int* __restrict__ counts,
        int* __restrict__ partials, int n) {
    int t = threadIdx.x;
    int base = blockIdx.x * SCAN_CHUNK + t * 16;
    int s = 0;
    int m = (base < n) ? min(16, n - base) : 0;
    for (int i = 0; i < m; ++i) s += (counts[base + i] + 1) & ~1;
    __shared__ int red[256];
    red[t] = s;
    __syncthreads();
    for (int off = 128; off > 0; off >>= 1) {
        if (t < off) red[t] += red[t + off];
        __syncthreads();
    }
    if (t == 0) partials[blockIdx.x] = red[0];
}

// also zeroes the sentinel row n of ts while this tiny kernel is here
__global__ void scan_partials_kernel(int* __restrict__ partials, int nb,
                                     unsigned* __restrict__ ts_zero_row) {
    int t = threadIdx.x;
    if (t < 64) ts_zero_row[t] = 0;   // ts row n: 128 bf16 = 64 uints
    if (t == 0 && blockIdx.x == 0) {
        int run = 0;
        for (int i = 0; i < nb; ++i) { int c = partials[i]; partials[i] = run; run += c; }
        partials[nb] = run;   // total (padded)
    }
}

__global__ __launch_bounds__(256) void scan_emit_kernel(const int* __restrict__ counts,
        const int* __restrict__ partials, int* __restrict__ row_start,
        int* __restrict__ cursor, float* __restrict__ dis,
        int* __restrict__ csr, int n, int nb) {
    int t = threadIdx.x;
    int base = blockIdx.x * SCAN_CHUNK + t * 16;
    int cnt[16];
    int s = 0;
    int m = (base < n) ? min(16, n - base) : 0;
    for (int i = 0; i < m; ++i) { cnt[i] = counts[base + i]; s += (cnt[i] + 1) & ~1; }
    __shared__ int red[256];
    red[t] = s;
    __syncthreads();
    for (int off = 1; off < 256; off <<= 1) {   // inclusive Hillis-Steele
        int v = red[t];
        int vo = (t >= off) ? red[t - off] : 0;
        __syncthreads();
        red[t] = v + vo;
        __syncthreads();
    }
    int run = partials[blockIdx.x] + (t ? red[t - 1] : 0);
    for (int i = 0; i < m; ++i) {
        int c = cnt[i];
        row_start[base + i] = run;
        cursor[base + i] = run;
        dis[base + i] = rsqrtf((float)(c + 1));   // deg = REAL indeg + self-loop
        if (c & 1) csr[run + c] = n;              // pad slot -> sentinel zero row
        run += (c + 1) & ~1;
    }
    if (blockIdx.x == 0 && t == 0) row_start[n] = partials[nb];
}

__global__ void scatter_kernel(const int* __restrict__ srcA, const int* __restrict__ dstA,
                               int* __restrict__ cursor, int* __restrict__ csr,
                               int E, int n) {
    int e = blockIdx.x * blockDim.x + threadIdx.x;
    if (e < E) {
        int d = dstA[e];
        int s = srcA[e];
        if ((unsigned)d < (unsigned)n && (unsigned)s < (unsigned)n) {
            int p = atomicAdd(&cursor[d], 1);
            csr[p] = s;
        }
    }
}

// xs[i,:] = bf16(dis[i] * x[i,:]) for i<n;  xs[n,:] = 0 (sentinel row)
__global__ void scale_cast_kernel(const float* __restrict__ x, const float* __restrict__ dis,
                                  u16* __restrict__ xs, int n) {
    int gid = blockIdx.x * blockDim.x + threadIdx.x;
    int total = (n + 1) * (IN_DIM / 4);
    if (gid >= total) return;
    int node = gid >> 6;   // IN_DIM/4 == 64
    uint2 o = make_uint2(0, 0);
    if (node < n) {
        float4 v = ((const float4*)x)[gid];
        float d = dis[node];
        o.x = (unsigned)f2bf(v.x * d) | ((unsigned)f2bf(v.y * d) << 16);
        o.y = (unsigned)f2bf(v.z * d) | ((unsigned)f2bf(v.w * d) << 16);
    }
    ((uint2*)xs)[gid] = o;
}

// ---- aggregation 1: aggx[d] = bf16( dis[d] * (xs[d] + sum_{s in in(d)} xs[s]) ) -----
// Dual-row gather: lower/upper 32 lanes take rows j / j+1 at 16B/lane (uint4).

__global__ __launch_bounds__(256) void agg1_kernel(const u16* __restrict__ xs,
        const int* __restrict__ row_start, const int* __restrict__ csr,
        const float* __restrict__ dis, u16* __restrict__ aggx, int n) {
    int gid = blockIdx.x * blockDim.x + threadIdx.x;
    int w = gid >> 6, lane = gid & 63;
    if (w >= n) return;
    const uint4* base = (const uint4*)xs;       // 32 uint4 per 256-feat row
    int half = lane >> 5, hl = lane & 31;
    float a0 = 0.f, a1 = 0.f, a2 = 0.f, a3 = 0.f, a4 = 0.f, a5 = 0.f, a6 = 0.f, a7 = 0.f;
    if (half == 0) {                            // self-loop seed in lower half only
        uint4 u = base[(size_t)w * 32 + hl];
        a0 = bflo(u.x); a1 = bfhi(u.x); a2 = bflo(u.y); a3 = bfhi(u.y);
        a4 = bflo(u.z); a5 = bfhi(u.z); a6 = bflo(u.w); a7 = bfhi(u.w);
    }
    int b = row_start[w], e = row_start[w + 1];
    int i = b;
    for (; i + 8 <= e; i += 8) {
        int s0 = csr[i + half],     s1 = csr[i + 2 + half];
        int s2 = csr[i + 4 + half], s3 = csr[i + 6 + half];
        uint4 u0 = base[(size_t)s0 * 32 + hl];
        uint4 u1 = base[(size_t)s1 * 32 + hl];
        uint4 u2 = base[(size_t)s2 * 32 + hl];
        uint4 u3 = base[(size_t)s3 * 32 + hl];
        a0 += (bflo(u0.x) + bflo(u1.x)) + (bflo(u2.x) + bflo(u3.x));
        a1 += (bfhi(u0.x) + bfhi(u1.x)) + (bfhi(u2.x) + bfhi(u3.x));
        a2 += (bflo(u0.y) + bflo(u1.y)) + (bflo(u2.y) + bflo(u3.y));
        a3 += (bfhi(u0.y) + bfhi(u1.y)) + (bfhi(u2.y) + bfhi(u3.y));
        a4 += (bflo(u0.z) + bflo(u1.z)) + (bflo(u2.z) + bflo(u3.z));
        a5 += (bfhi(u0.z) + bfhi(u1.z)) + (bfhi(u2.z) + bfhi(u3.z));
        a6 += (bflo(u0.w) + bflo(u1.w)) + (bflo(u2.w) + bflo(u3.w));
        a7 += (bfhi(u0.w) + bfhi(u1.w)) + (bfhi(u2.w) + bfhi(u3.w));
    }
    for (; i < e; i += 2) {
        int s = csr[i + half];
        uint4 u = base[(size_t)s * 32 + hl];
        a0 += bflo(u.x); a1 += bfhi(u.x); a2 += bflo(u.y); a3 += bfhi(u.y);
        a4 += bflo(u.z); a5 += bfhi(u.z); a6 += bflo(u.w); a7 += bfhi(u.w);
    }
    a0 += __shfl_xor(a0, 32); a1 += __shfl_xor(a1, 32);
    a2 += __shfl_xor(a2, 32); a3 += __shfl_xor(a3, 32);
    a4 += __shfl_xor(a4, 32); a5 += __shfl_xor(a5, 32);
    a6 += __shfl_xor(a6, 32); a7 += __shfl_xor(a7, 32);
    if (half == 0) {
        float dd = dis[w];
        uint4 o;
        o.x = (unsigned)f2bf(a0 * dd) | ((unsigned)f2bf(a1 * dd) << 16);
        o.y = (unsigned)f2bf(a2 * dd) | ((unsigned)f2bf(a3 * dd) << 16);
        o.z = (unsigned)f2bf(a4 * dd) | ((unsigned)f2bf(a5 * dd) << 16);
        o.w = (unsigned)f2bf(a6 * dd) | ((unsigned)f2bf(a7 * dd) << 16);
        ((uint4*)aggx)[(size_t)w * 32 + hl] = o;
    }
}

// ---- GEMM1: feat1 = dropout(prelu(aggx @ W1 + b1)) -> bf16 ----------------
// DMA staging (R13, measured win): global_load_lds width=16, unpadded rows,
// XOR seg swizzle (seg' = seg ^ (row&7)).

__global__ __launch_bounds__(256) void gemm1_kernel(const u16* __restrict__ A,
        const u16* __restrict__ Bt, const float* __restrict__ bias,
        const float* __restrict__ a_p, const u64* __restrict__ mbits,
        u16* __restrict__ out, int M) {
    const int K = IN_DIM;
    __shared__ __align__(16) u16 As[BM * 64];   // 16 KB, unpadded
    __shared__ __align__(16) u16 Bs[BM * 64];   // 16 KB
    int tid = threadIdx.x;
    int wave = tid >> 6, lane = tid & 63;
    int quad = lane >> 4, l16 = lane & 15;
    int wm = wave & 1, wn = wave >> 1;
    int m0 = blockIdx.x * BM, n0 = blockIdx.y * BM;

    int r8 = lane >> 3, seg = lane & 7;
    int segx = seg ^ r8;                        // global seg fetched by this lane
    int l7 = l16 & 7;                           // row&7 for fragment reads

    floatx4 acc[4][4];
#pragma unroll
    for (int i = 0; i < 4; i++)
#pragma unroll
        for (int j = 0; j < 4; j++) acc[i][j] = (floatx4){0.f, 0.f, 0.f, 0.f};

    for (int k0 = 0; k0 < K; k0 += BKK) {
        __syncthreads();                        // prev-iter fragment reads done
#pragma unroll
        for (int c = 0; c < 4; c++) {
            int rl = (wave * 4 + c) * 8 + r8;   // local row 0..127
            int gra = m0 + rl; if (gra >= M) gra = M - 1;  // clamp; discarded in epilogue
            gl_lds16(A  + (size_t)gra * K        + k0 + segx * 8, &As[(wave * 4 + c) * 512]);
            gl_lds16(Bt + (size_t)(n0 + rl) * K  + k0 + segx * 8, &Bs[(wave * 4 + c) * 512]);
        }
        __syncthreads();                        // vmcnt drain: tiles visible
        short8 bf8[4][2];
#pragma unroll
        for (int i = 0; i < 4; i++)
#pragma unroll
            for (int ks = 0; ks < 2; ks++)
                bf8[i][ks] = *(const short8*)&Bs[(wn * 64 + i * 16 + l16) * 64
                                                 + (((ks * 4 + quad) ^ l7) * 8)];
#pragma unroll
        for (int mt = 0; mt < 4; mt++) {
            short8 af0 = *(const short8*)&As[(wm * 64 + mt * 16 + l16) * 64 + ((quad ^ l7) * 8)];
            short8 af1 = *(const short8*)&As[(wm * 64 + mt * 16 + l16) * 64 + (((4 + quad) ^ l7) * 8)];
#pragma unroll
            for (int nt = 0; nt < 4; nt++) {
                acc[mt][nt] = __builtin_amdgcn_mfma_f32_16x16x32_bf16(
                    af0, bf8[nt][0], acc[mt][nt], 0, 0, 0);
                acc[mt][nt] = __builtin_amdgcn_mfma_f32_16x16x32_bf16(
                    af1, bf8[nt][1], acc[mt][nt], 0, 0, 0);
            }
        }
    }

    // stage this block's mask bits (128 rows x 4 u64, stride 5 -> 5KB, alias As)
    u64* mb = (u64*)As;
    __syncthreads();
    for (int u = tid; u < BM * 4; u += 256) {
        int row = u >> 2, j = u & 3;
        int gr = m0 + row;
        u64 val = 0;
        if (gr < M) val = mbits[(size_t)gr * 8 + (n0 >> 8) * 4 + j];
        mb[row * 5 + j] = val;
    }
    __syncthreads();

    float alpha = a_p[0];
#pragma unroll
    for (int mt = 0; mt < 4; mt++) {
#pragma unroll
        for (int r = 0; r < 4; r++) {
            int lr = wm * 64 + mt * 16 + quad * 4 + r;   // local row in [0,128)
            int row = m0 + lr;
            if (row >= M) continue;
#pragma unroll
            for (int nt = 0; nt < 4; nt++) {
                int c64 = nt * 16 + l16;                 // col within wn's 64-col half
                int col = n0 + wn * 64 + c64;
                float v = acc[mt][nt][r] + bias[col];
                v = (v >= 0.f) ? v : alpha * v;
                u64 w = mb[lr * 5 + (l16 & 3)];          // j = col & 3 == l16 & 3
                int bit = ((n0 >> 2) + wn * 16 + nt * 4 + (l16 >> 2)) & 63;  // (col>>2)&63
                v = ((w >> bit) & 1ull) ? v * 2.0f : 0.0f;
                out[(size_t)row * H1 + col] = f2bf(v);
            }
        }
    }
}

// ---- GEMM2: ts = bf16( dis[row] * (feat1 @ W2) ) --------------------------
// DMA staging (ported from gemm1's R13 win): 24 chunks of 8 rows x 128B per
// K-iter (A: 8, B: 16), 6 per wave; XOR seg swizzle, unpadded 64-short rows.

__global__ __launch_bounds__(256) void gemm2_kernel(const u16* __restrict__ A,
        const u16* __restrict__ Bt, const float* __restrict__ dis,
        u16* __restrict__ out, int M) {
    const int K = H1;
    __shared__ __align__(16) u16 As[64 * 64];    // 8 KB, unpadded
    __shared__ __align__(16) u16 Bs[128 * 64];   // 16 KB
    int tid = threadIdx.x;
    int wave = tid >> 6, lane = tid & 63;
    int quad = lane >> 4, l16 = lane & 15;
    int wm = wave & 1, wn = wave >> 1;
    int m0 = blockIdx.x * 64;

    int r8 = lane >> 3, seg = lane & 7;
    int segx = seg ^ r8;
    int l7 = l16 & 7;

    floatx4 acc[2][4];
#pragma unroll
    for (int i = 0; i < 2; i++)
#pragma unroll
        for (int j = 0; j < 4; j++) acc[i][j] = (floatx4){0.f, 0.f, 0.f, 0.f};

    for (int k0 = 0; k0 < K; k0 += BKK) {
        __syncthreads();
#pragma unroll
        for (int c = 0; c < 6; c++) {            // wave-uniform chunk assignment
            int ch = wave * 6 + c;               // 0..23: ch<8 -> A, else B
            if (ch < 8) {
                int rl = ch * 8 + r8;            // local A row 0..63
                int gra = m0 + rl; if (gra >= M) gra = M - 1;
                gl_lds16(A + (size_t)gra * K + k0 + segx * 8, &As[ch * 512]);
            } else {
                int rl = (ch - 8) * 8 + r8;      // B row 0..127
                gl_lds16(Bt + (size_t)rl * K + k0 + segx * 8, &Bs[(ch - 8) * 512]);
            }
        }
        __syncthreads();
        short8 bf8[4][2];
#pragma unroll
        for (int i = 0; i < 4; i++)
#pragma unroll
            for (int ks = 0; ks < 2; ks++)
                bf8[i][ks] = *(const short8*)&Bs[(wn * 64 + i * 16 + l16) * 64
                                                 + (((ks * 4 + quad) ^ l7) * 8)];
#pragma unroll
        for (int mt = 0; mt < 2; mt++) {
            short8 af0 = *(const short8*)&As[(wm * 32 + mt * 16 + l16) * 64 + ((quad ^ l7) * 8)];
            short8 af1 = *(const short8*)&As[(wm * 32 + mt * 16 + l16) * 64 + (((4 + quad) ^ l7) * 8)];
#pragma unroll
            for (int nt = 0; nt < 4; nt++) {
                acc[mt][nt] = __builtin_amdgcn_mfma_f32_16x16x32_bf16(
                    af0, bf8[nt][0], acc[mt][nt], 0, 0, 0);
                acc[mt][nt] = __builtin_amdgcn_mfma_f32_16x16x32_bf16(
                    af1, bf8[nt][1], acc[mt][nt], 0, 0, 0);
            }
        }
    }

#pragma unroll
    for (int mt = 0; mt < 2; mt++) {
#pragma unroll
        for (int r = 0; r < 4; r++) {
            int row = m0 + wm * 32 + mt * 16 + quad * 4 + r;
            if (row >= M) continue;
            float dd = dis[row];
#pragma unroll
            for (int nt = 0; nt < 4; nt++) {
                int col = wn * 64 + nt * 16 + l16;
                out[(size_t)row * H2 + col] = f2bf(acc[mt][nt][r] * dd);
            }
        }
    }
}

// ---- aggregation 2 + epilogue: out = dropout(prelu(dis[d]*(ts[d]+sum ts[s]) + b2)) --
// Dual-row gather (uint2, 8B/lane), padded-even CSR, float4 epilogue.

__global__ __launch_bounds__(256) void agg2_kernel(const u16* __restrict__ ts,
        const int* __restrict__ row_start, const int* __restrict__ csr,
        const float* __restrict__ dis, const float* __restrict__ b2,
        const float* __restrict__ a_p, const int* __restrict__ mask,
        float* __restrict__ out, int n) {
    int gid = blockIdx.x * blockDim.x + threadIdx.x;
    int w = gid >> 6, lane = gid & 63;
    if (w >= n) return;
    const uint2* base = (const uint2*)ts;   // 32 uint2 per 128-feat row
    int half = lane >> 5, hl = lane & 31;
    float a0 = 0.f, a1 = 0.f, a2 = 0.f, a3 = 0.f;
    if (half == 0) {                        // self-loop seed
        uint2 u = base[(size_t)w * 32 + hl];
        a0 = bflo(u.x); a1 = bfhi(u.x); a2 = bflo(u.y); a3 = bfhi(u.y);
    }
    int b = row_start[w], e = row_start[w + 1];
    int i = b;
    for (; i + 8 <= e; i += 8) {
        int s0 = csr[i + half],     s1 = csr[i + 2 + half];
        int s2 = csr[i + 4 + half], s3 = csr[i + 6 + half];
        uint2 u0 = base[(size_t)s0 * 32 + hl];
        uint2 u1 = base[(size_t)s1 * 32 + hl];
        uint2 u2 = base[(size_t)s2 * 32 + hl];
        uint2 u3 = base[(size_t)s3 * 32 + hl];
        a0 += (bflo(u0.x) + bflo(u1.x)) + (bflo(u2.x) + bflo(u3.x));
        a1 += (bfhi(u0.x) + bfhi(u1.x)) + (bfhi(u2.x) + bfhi(u3.x));
        a2 += (bflo(u0.y) + bflo(u1.y)) + (bflo(u2.y) + bflo(u3.y));
        a3 += (bfhi(u0.y) + bfhi(u1.y)) + (bfhi(u2.y) + bfhi(u3.y));
    }
    for (; i < e; i += 2) {
        int s = csr[i + half];
        uint2 u = base[(size_t)s * 32 + hl];
        a0 += bflo(u.x); a1 += bfhi(u.x); a2 += bflo(u.y); a3 += bfhi(u.y);
    }
    a0 += __shfl_xor(a0, 32); a1 += __shfl_xor(a1, 32);
    a2 += __shfl_xor(a2, 32); a3 += __shfl_xor(a3, 32);
    if (half == 0) {
        float dd = dis[w];
        float alpha = a_p[0];
        float4 bb = ((const float4*)b2)[hl];
        float v0 = dd * a0 + bb.x;
        float v1 = dd * a1 + bb.y;
        float v2 = dd * a2 + bb.z;
        float v3 = dd * a3 + bb.w;
        v0 = (v0 >= 0.f) ? v0 : alpha * v0;
        v1 = (v1 >= 0.f) ? v1 : alpha * v1;
        v2 = (v2 >= 0.f) ? v2 : alpha * v2;
        v3 = (v3 >= 0.f) ? v3 : alpha * v3;
        int4 m = ((const int4*)mask)[(size_t)w * 32 + hl];
        v0 = m.x ? v0 * 2.f : 0.f;
        v1 = m.y ? v1 * 2.f : 0.f;
        v2 = m.z ? v2 * 2.f : 0.f;
        v3 = m.w ? v3 * 2.f : 0.f;
        ((float4*)out)[(size_t)w * 32 + hl] = make_float4(v0, v1, v2, v3);
    }
}

// ---- launch ---------------------------------------------------------------

extern "C" void kernel_launch(void* const* d_in, const int* in_sizes, int n_in,
                              void* d_out, int out_size, void* d_ws, size_t ws_size,
                              hipStream_t stream) {
    const float* x  = (const float*)d_in[0];
    const int* ei   = (const int*)d_in[1];
    const float* W1 = (const float*)d_in[2];
    const float* b1 = (const float*)d_in[3];
    const float* W2 = (const float*)d_in[4];
    const float* b2 = (const float*)d_in[5];
    const float* ap = (const float*)d_in[6];
    const int* mask1 = (const int*)d_in[7];
    const int* mask2 = (const int*)d_in[8];

    int n = in_sizes[0] / IN_DIM;      // 50000
    int E = in_sizes[1] / 2;           // 400000
    const int* srcA = ei;
    const int* dstA = ei + E;

    // ws layout (aliased lifetimes):
    //   feat1 (n*H1 bf16); first half doubles as xs (n+1 rows incl. sentinel)
    //   ts ((n+1)*H2 bf16; doubles as mask1 bitpack before gemm2 writes ts),
    //   w1t, w2t, dis, counts, cursor, row_start, csr (E + n pad), partials
    // aggx (n*IN_DIM bf16) lives in d_out (dead before agg2 rewrites d_out).
    char* p = (char*)d_ws;
    auto alloc = [&](size_t bytes) {
        char* r = p;
        p += (bytes + 255) & ~(size_t)255;
        return r;
    };
    u16* feat1     = (u16*)alloc((size_t)n * H1 * 2);
    u16* xs        = feat1;            // alias: xs dead before feat1 is written
    u16* ts        = (u16*)alloc((size_t)(n + 1) * H2 * 2);
    u64* bits1     = (u64*)ts;         // alias: bits1 (3.2MB) dead before gemm2 writes ts
    u16* w1t       = (u16*)alloc((size_t)IN_DIM * H1 * 2);
    u16* w2t       = (u16*)alloc((size_t)H1 * H2 * 2);
    float* dis     = (float*)alloc((size_t)n * 4);
    int* counts    = (int*)alloc((size_t)n * 4);
    int* cursor    = (int*)alloc((size_t)n * 4);
    int* row_start = (int*)alloc(((size_t)n + 1) * 4);
    int* csr       = (int*)alloc(((size_t)E + n + 64) * 4);
    int nscan = (n + SCAN_CHUNK - 1) / SCAN_CHUNK;
    int* partials  = (int*)alloc(((size_t)nscan + 1) * 4);
    u16* aggx      = (u16*)d_out;      // n*IN_DIM*2 == out_size*4 bytes exactly
    if ((size_t)(p - (char*)d_ws) > ws_size) return;  // ws too small: leave zeros

    const int tpb = 256;
    int total4 = n * H1 / 4;           // int4 elements; divisible by 256
    int PB = (total4 + tpb - 1) / tpb;
    int HB = (E + tpb - 1) / tpb;
    int T1B = (IN_DIM * H1 + tpb - 1) / tpb;
    int T2B = (H1 * H2 + tpb - 1) / tpb;
    hipMemsetAsync(counts, 0, (size_t)n * 4, stream);
    prep_kernel<<<PB + HB + T1B + T2B, tpb, 0, stream>>>((const int4*)mask1, bits1, total4,
        dstA, counts, E, n, W1, w1t, W2, w2t, PB, HB, T1B);
    partial_sum_kernel<<<nscan, tpb, 0, stream>>>(counts, partials, n);
    scan_partials_kernel<<<1, 64, 0, stream>>>(partials, nscan,
        (unsigned*)(ts + (size_t)n * H2));
    scan_emit_kernel<<<nscan, tpb, 0, stream>>>(counts, partials, row_start, cursor, dis,
                                                csr, n, nscan);
    scatter_kernel<<<(E + tpb - 1) / tpb, tpb, 0, stream>>>(srcA, dstA, cursor, csr, E, n);
    scale_cast_kernel<<<(((n + 1) * (IN_DIM / 4)) + tpb - 1) / tpb, tpb, 0, stream>>>(x, dis, xs, n);
    agg1_kernel<<<(n * 64 + tpb - 1) / tpb, tpb, 0, stream>>>(xs, row_start, csr, dis, aggx, n);
    dim3 g1((n + BM - 1) / BM, H1 / BM);
    gemm1_kernel<<<g1, tpb, 0, stream>>>(aggx, w1t, b1, ap, bits1, feat1, n);
    dim3 g2((n + 63) / 64, 1);
    gemm2_kernel<<<g2, tpb, 0, stream>>>(feat1, w2t, dis, ts, n);
    agg2_kernel<<<(n * 64 + tpb - 1) / tpb, tpb, 0, stream>>>(ts, row_start, csr, dis, b2, ap,
                                                              mask2, (float*)d_out, n);
}